// Round 9
// baseline (169.471 us; speedup 1.0000x reference)
//
#include <hip/hip_runtime.h>
#include <hip/hip_bf16.h>
#include <math.h>
#include <stdint.h>

#define S    256
#define GN   128

typedef __attribute__((ext_vector_type(8))) short  short8;   // 8 bf16
typedef __attribute__((ext_vector_type(4))) float  floatx4;  // MFMA C/D
typedef __attribute__((ext_vector_type(2))) float  float2v;  // v_pk_*_f32 pair

// workspace layout (bytes)
#define WS_BHI 0          // ushort[4*4*64*8] = 16384 B  (f_w2 bf16, frag order)
#define WS_RW1 16384      // ushort[2*4*64*8] =  8192 B  (r_w1 bf16, frag order)
#define WS_B2S 24576      // float  (b2.s_w + s_b)
#define WS_WS2 24592      // float[128]  (W2 @ s_w, fp32)
#define WS_W1P 25104      // float[64*8] pair-interleaved layer-1 = 2048 B
#define WS_W2E 27152      // ushort[2*64*8] = 2048 B (r_w2^T bf16, A-frag order)

__device__ __forceinline__ unsigned short bf16_rtne(float f) {
    uint32_t u = __builtin_bit_cast(uint32_t, f);
    uint32_t r = (u + 0x7fffu + ((u >> 16) & 1u)) >> 16;
    return (unsigned short)r;
}
__device__ __forceinline__ uint32_t cvt_pk_bf16(float a, float b) {
    float2 hh; hh.x = a; hh.y = b;
    __hip_bfloat162 pk = __float22bfloat162_rn(hh);   // v_cvt_pk_bf16_f32
    uint32_t u; __builtin_memcpy(&u, &pk, 4);
    return u;
}

// ---------- pre-pack kernel: weights -> bf16 in MFMA fragment order ----------
__global__ __launch_bounds__(256)
void nerf_prep(const float* __restrict__ f_w1, const float* __restrict__ f_b1,
               const float* __restrict__ f_w2, const float* __restrict__ f_b2,
               const float* __restrict__ s_w,  const float* __restrict__ s_b,
               const float* __restrict__ r_w1, const float* __restrict__ r_w2,
               unsigned char* __restrict__ ws)
{
    const int tid = threadIdx.x;
    if (tid < 128) {                       // ws2 = W2 @ s_w  (fp32) -> global
        float acc = 0.0f;
        for (int n = 0; n < 64; ++n) acc += f_w2[tid * 64 + n] * s_w[n];
        ((float*)(ws + WS_WS2))[tid] = acc;
    } else if (tid == 128) {               // b2s = b2 . s_w + s_b
        float acc = s_b[0];
        for (int n = 0; n < 64; ++n) acc += f_b2[n] * s_w[n];
        *(float*)(ws + WS_B2S) = acc;
    }
    // layer-1 pair-interleaved pack: pair pp covers k=2pp,2pp+1:
    //   {wx0,wx1, wy0,wy1, wz0,wz1, b0,b1}  (aligned float2 pairs for v_pk_fma)
    {
        float* w1pk = (float*)(ws + WS_W1P);
        for (int pp = tid; pp < 64; pp += 256) {
            int k0 = 2 * pp, k1 = 2 * pp + 1;
            w1pk[pp * 8 + 0] = f_w1[k0];       w1pk[pp * 8 + 1] = f_w1[k1];
            w1pk[pp * 8 + 2] = f_w1[128 + k0]; w1pk[pp * 8 + 3] = f_w1[128 + k1];
            w1pk[pp * 8 + 4] = f_w1[256 + k0]; w1pk[pp * 8 + 5] = f_w1[256 + k1];
            w1pk[pp * 8 + 6] = f_b1[k0];       w1pk[pp * 8 + 7] = f_b1[k1];
        }
    }

    unsigned short* bhi = (unsigned short*)(ws + WS_BHI);
    for (int i = tid; i < 8192; i += 256) {
        int j = i & 7, L = (i >> 3) & 63, g = i >> 9;   // g = kc*4 + tn
        int tn = g & 3, kc = g >> 2;
        int q = L >> 4, cc = L & 15;
        int k = kc * 32 + q * 8 + j;
        bhi[i] = bf16_rtne(f_w2[k * 64 + tn * 16 + cc]);
    }
    unsigned short* rw = (unsigned short*)(ws + WS_RW1);
    for (int i = tid; i < 4096; i += 256) {
        int j = i & 7, L = (i >> 3) & 63, g = i >> 9;   // g = ks*4 + tn
        int tn = g & 3, ks = g >> 2;
        int q = L >> 4, cc = L & 15;
        int k = ks * 32 + q * 8 + j;
        rw[i] = bf16_rtne(r_w1[k * 64 + tn * 16 + cc]);
    }
    // r_w2^T in A-fragment order for the phase-E MFMA:
    // A[row=out-channel][k=hidden]; rows 3..15 zero.
    unsigned short* w2e = (unsigned short*)(ws + WS_W2E);
    for (int i = tid; i < 1024; i += 256) {
        int j = i & 7, L = (i >> 3) & 63, kf = i >> 9;
        int q = L >> 4, ch = L & 15;
        int k = kf * 32 + q * 8 + j;
        w2e[i] = (ch < 3) ? bf16_rtne(r_w2[k * 3 + ch]) : (unsigned short)0;
    }
}

// ---------------------------- main kernel -----------------------------------
// R26 = R25 + scan/partials moved from global out[]-slots into spare w1s LDS.
// R25 post-mortem: barrier deletion was exactly neutral (88.0 vs 87.6) -- the
// fifth structurally-distinct variant at 88 +- 0.5 us. Revised model: VALU
// time is dominated by address arithmetic + packing glue around the LDS
// transposes (the MLP math is only ~800 cyc/wave of the ~7k VALU cyc/wave),
// which is structural. Remaining safe residual: R20's global out[]-slot scan
// round-trip (write -> barrier -> L2 read ~200-300cyc exposed per block)
// existed only to hit LDS=32768; at 35328 the constraint is moot. sWaveSum ->
// w1s[640..643], sPart -> w1s[644..655]; straddle kept (write before phase D,
// read after). out[] now written exactly once at the end.
// COMMITMENT: if this lands >= 87.5, every safe lever is exhausted (occupancy
// R21, VMEM staging R24, pipelining R22-spill, barriers R25, scan RT R23/R26)
// and next round declares the ceiling.
__global__ __launch_bounds__(256, 4)
void nerf_mfma(const float* __restrict__ rays_o,
               const float* __restrict__ rays_d,
               const float* __restrict__ grid,
               const float* __restrict__ f_b2,
               const float* __restrict__ r_w1,
               const float* __restrict__ r_b1,
               const float* __restrict__ r_b2,
               const unsigned char* __restrict__ ws,
               float* __restrict__ out)
{
    // fh: bf16 [256 rows][64], XOR-swizzled in 8-ushort groups: conflict-free
    // b128. Wave-private throughout.
    __shared__ __align__(16) unsigned short fh[256 * 64];
    // w1s: [0..511] layer-1 pack, [512..639] ws2, [640..643] sWaveSum,
    //      [644..655] sPart. 2624 B; total LDS 35392 -> still 4 blocks/CU.
    __shared__ __align__(16) float w1s[656];

    const int tid   = threadIdx.x;
    const int ray   = blockIdx.x;
    const int lane  = tid & 63;
    const int wv    = tid >> 6;
    const int q     = lane >> 4;
    const int c     = lane & 15;
    const int mbase = wv * 64;
    const int d01   = 72 - ((c >> 3) << 4);   // i1 - i0 in the epilogue swizzle

    // stage layer-1 pack (2 KB) + ws2 (512 B) into dedicated LDS
    if (tid < 128) {
        ((float4*)w1s)[tid] = ((const float4*)(ws + WS_W1P))[tid];
        w1s[512 + tid]      = ((const float*)(ws + WS_WS2))[tid];
    }

    // ---------------- Phase A: geometry + grid sample (thread = sample) ------
    const float stop = 1.0f - 1.0f / (float)(S + 2);
    const float step = stop / (float)S;
    float u0 = (float)tid * step;
    float u1 = (float)(tid + 1) * step;
    float t    = (u0 < 0.5f) ? 2.0f * u0 : 1.0f / (2.0f - 2.0f * u0);
    float tn_  = (u1 < 0.5f) ? 2.0f * u1 : 1.0f / (2.0f - 2.0f * u1);
    float dist = tn_ - t;

    float ox = rays_o[ray * 3 + 0], oy = rays_o[ray * 3 + 1], oz = rays_o[ray * 3 + 2];
    float dxv = rays_d[ray * 3 + 0], dyv = rays_d[ray * 3 + 1], dzv = rays_d[ray * 3 + 2];

    float px = ox + dxv * t, py = oy + dyv * t, pz = oz + dzv * t;
    float nrm = sqrtf(px * px + py * py + pz * pz);
    float scale = (nrm <= 1.0f) ? 0.5f : (2.0f - 1.0f / nrm) / nrm * 0.5f;
    float cx = px * scale, cy = py * scale, cz = pz * scale;

    float ix = ((cx + 1.0f) * (float)GN - 1.0f) * 0.5f;
    float iy = ((cy + 1.0f) * (float)GN - 1.0f) * 0.5f;
    float iz = ((cz + 1.0f) * (float)GN - 1.0f) * 0.5f;
    float fx0 = floorf(ix), fy0 = floorf(iy), fz0 = floorf(iz);
    float fx = ix - fx0, fy = iy - fy0, fz = iz - fz0;
    int x0 = (int)fx0, y0 = (int)fy0, z0 = (int)fz0;
    int x1 = x0 + 1, y1 = y0 + 1, z1 = z0 + 1;

    // contracted coords strictly inside [-1,1] -> x0 in [-1,127], x1 in [0,128].
    // Only boundary taps can be invalid: zero the per-axis weight, clamp the
    // index. 0*g == 0 exactly; product order (wx*wy)*wz matches branchy version.
    float wxv[2], wyv[2], wzv[2];
    wxv[0] = (x0 >= 0) ? (1.0f - fx) : 0.0f;  wxv[1] = (x1 < GN) ? fx : 0.0f;
    wyv[0] = (y0 >= 0) ? (1.0f - fy) : 0.0f;  wyv[1] = (y1 < GN) ? fy : 0.0f;
    wzv[0] = (z0 >= 0) ? (1.0f - fz) : 0.0f;  wzv[1] = (z1 < GN) ? fz : 0.0f;
    int xc[2], yb[2], zb[2];
    xc[0] = (x0 < 0) ? 0 : x0;              xc[1] = (x1 > GN - 1) ? GN - 1 : x1;
    yb[0] = ((y0 < 0) ? 0 : y0) * GN;       yb[1] = ((y1 > GN - 1) ? GN - 1 : y1) * GN;
    zb[0] = ((z0 < 0) ? 0 : z0) * (GN*GN);  zb[1] = ((z1 > GN - 1) ? GN - 1 : z1) * (GN*GN);

    float occ = 0.0f;
    #pragma unroll
    for (int dzc = 0; dzc < 2; ++dzc)
    #pragma unroll
    for (int dyc = 0; dyc < 2; ++dyc)
    #pragma unroll
    for (int dxc = 0; dxc < 2; ++dxc) {
        float w = (wxv[dxc] * wyv[dyc]) * wzv[dzc];
        occ += w * grid[zb[dzc] + yb[dyc] + xc[dxc]];
    }
    bool maskA = occ > 0.01f;

    __syncthreads();   // w1s staged

    // ------- Phase B+C: feat GEMM in two tm-passes (acc[2][4] = 32 AGPR) -----
    const unsigned short* __restrict__ bhiP = (const unsigned short*)(ws + WS_BHI);
    float sgv[4] = {0.0f, 0.0f, 0.0f, 0.0f};   // all reads/writes literal-indexed

    #pragma unroll 1
    for (int ph = 0; ph < 2; ++ph) {
        // coords of the A-fragment rows for THIS pass (literal-indexed pair;
        // ph only appears in the shuffle source lane -> no scratch)
        float cxs[2], cys[2], czs[2];
        #pragma unroll
        for (int tm = 0; tm < 2; ++tm) {
            int src = (ph * 2 + tm) * 16 + c;
            cxs[tm] = __shfl(cx, src, 64);
            cys[tm] = __shfl(cy, src, 64);
            czs[tm] = __shfl(cz, src, 64);
        }

        floatx4 acc[2][4];
        {
            float b2v[4];
            #pragma unroll
            for (int tn = 0; tn < 4; ++tn) b2v[tn] = f_b2[tn * 16 + c];
            #pragma unroll
            for (int tm = 0; tm < 2; ++tm)
                #pragma unroll
                for (int tn = 0; tn < 4; ++tn) {
                    floatx4 v; v[0] = b2v[tn]; v[1] = b2v[tn]; v[2] = b2v[tn]; v[3] = b2v[tn];
                    acc[tm][tn] = v;
                }
        }
        float2v sig2[2];
        sig2[0][0] = 0.0f; sig2[0][1] = 0.0f;
        sig2[1][0] = 0.0f; sig2[1][1] = 0.0f;

        #pragma unroll 2
        for (int kc = 0; kc < 4; ++kc) {
            const int k0  = kc * 32 + q * 8;
            const int pp0 = kc * 16 + q * 4;
            const float4* w1q4 = (const float4*)&w1s[pp0 * 8];
            float ws2r[8];
            *(float4*)(ws2r)     = *(const float4*)&w1s[512 + k0];
            *(float4*)(ws2r + 4) = *(const float4*)&w1s[512 + k0 + 4];

            uint32_t packed[2][4];
            #pragma unroll
            for (int p = 0; p < 4; ++p) {
                float4 q0 = w1q4[2 * p];         // {wx0,wx1, wy0,wy1}
                float4 q1 = w1q4[2 * p + 1];     // {wz0,wz1, b0, b1}
                float2v wx2 = {q0.x, q0.y};
                float2v wy2 = {q0.z, q0.w};
                float2v wz2 = {q1.x, q1.y};
                float2v bb2 = {q1.z, q1.w};
                float2v wsp = {ws2r[2 * p], ws2r[2 * p + 1]};
                #pragma unroll
                for (int tm = 0; tm < 2; ++tm) {
                    float2v h2 = bb2;
                    h2 = __builtin_elementwise_fma((float2v){cxs[tm], cxs[tm]}, wx2, h2);
                    h2 = __builtin_elementwise_fma((float2v){cys[tm], cys[tm]}, wy2, h2);
                    h2 = __builtin_elementwise_fma((float2v){czs[tm], czs[tm]}, wz2, h2);
                    h2 = __builtin_elementwise_max(h2, (float2v){0.0f, 0.0f});
                    sig2[tm] = __builtin_elementwise_fma(h2, wsp, sig2[tm]);
                    packed[tm][p] = cvt_pk_bf16(h2[0], h2[1]);
                }
            }
            short8 Ah[2];
            #pragma unroll
            for (int tm = 0; tm < 2; ++tm) {
                uint4 v4 = {packed[tm][0], packed[tm][1], packed[tm][2], packed[tm][3]};
                Ah[tm] = __builtin_bit_cast(short8, v4);
            }
            const int bbase = (kc * 4) * 512 + lane * 8;
            #pragma unroll
            for (int tn = 0; tn < 4; ++tn) {
                short8 bh = *(const short8*)(bhiP + bbase + tn * 512);
                #pragma unroll
                for (int tm = 0; tm < 2; ++tm)
                    acc[tm][tn] = __builtin_amdgcn_mfma_f32_16x16x32_bf16(Ah[tm], bh, acc[tm][tn], 0, 0, 0);
            }
        }

        // NO barrier: fh is wave-private (staging lives in w1s).

        // phase C for this pass: feat rows -> fh, sigma partials collapse
        #pragma unroll
        for (int tm = 0; tm < 2; ++tm)
            #pragma unroll
            for (int tn = 0; tn < 4; ++tn)
                #pragma unroll
                for (int pr = 0; pr < 2; ++pr) {
                    uint32_t u = cvt_pk_bf16(acc[tm][tn][2 * pr], acc[tm][tn][2 * pr + 1]);
                    int m0 = mbase + (ph * 2 + tm) * 16 + q * 4 + 2 * pr;
                    int i0 = m0 * 64 + c + (((tn * 2) ^ (m0 & 7)) << 3);
                    fh[i0]       = (unsigned short)u;
                    fh[i0 + d01] = (unsigned short)(u >> 16);
                }
        {
            float s0 = sig2[0][0] + sig2[0][1];
            s0 += __shfl_xor(s0, 16);
            s0 += __shfl_xor(s0, 32);
            float s1 = sig2[1][0] + sig2[1][1];
            s1 += __shfl_xor(s1, 16);
            s1 += __shfl_xor(s1, 32);
            if (ph == 0) { sgv[0] = s0; sgv[1] = s1; }   // wave-uniform branch,
            else         { sgv[2] = s0; sgv[3] = s1; }   // literal indices
        }
    }

    // ------- per-lane sigma: sgv[] is q-broadcast; own row = lane -> sgv[q] --
    float av;
    {
        float b2s = *(const float*)(ws + WS_B2S);
        float s01  = (q & 1) ? sgv[1] : sgv[0];
        float s23  = (q & 1) ? sgv[3] : sgv[2];
        float sa = ((q & 2) ? s23 : s01) + b2s;
        float sg = maskA ? (fmaxf(sa, 0.0f) + __logf(1.0f + __expf(-fabsf(sa)))) : 0.0f;
        av = -sg * dist;
    }

    // hd[] uniform loads: latency hides under the scan below
    float hd[4];
    #pragma unroll
    for (int tn = 0; tn < 4; ++tn) {
        int n = tn * 16 + c;
        hd[tn] = r_b1[n] + dxv * r_w1[64 * 64 + n] + dyv * r_w1[65 * 64 + n] + dzv * r_w1[66 * 64 + n];
    }

    // ---------------- transmittance scan, part 1 (intra-wave) ----------------
    float v = av;
    #pragma unroll
    for (int off = 1; off < 64; off <<= 1) {
        float u2 = __shfl_up(v, off);
        if (lane >= off) v += u2;
    }
    // LDS slot-write NOW; barrier + dependent read happen AFTER phase D, so
    // even the short LDS latency hides under the rgb-hidden GEMM.
    if (lane == 63 && wv < 3) w1s[640 + wv] = v;

    // ---------------- Phase D: rgb-hidden GEMM, two tm-passes ----------------
    const unsigned short* __restrict__ rwP = (const unsigned short*)(ws + WS_RW1);

    #pragma unroll 1
    for (int ph = 0; ph < 2; ++ph) {
        // pass-0 epilogue writes rows mbase+0..31; pass-1 afr reads rows
        // mbase+32..63 -- disjoint, wave-private: no barrier needed.
        short8 afr[2][2];
        #pragma unroll
        for (int tm = 0; tm < 2; ++tm)
            #pragma unroll
            for (int ks = 0; ks < 2; ++ks) {
                int m = mbase + (ph * 2 + tm) * 16 + c;
                int gl = ks * 4 + q;
                afr[tm][ks] = *(const short8*)&fh[m * 64 + ((gl ^ (m & 7)) << 3)];
            }

        floatx4 acc[2][4];
        #pragma unroll
        for (int tm = 0; tm < 2; ++tm)
            #pragma unroll
            for (int tn = 0; tn < 4; ++tn) {
                floatx4 z; z[0] = 0.0f; z[1] = 0.0f; z[2] = 0.0f; z[3] = 0.0f;
                acc[tm][tn] = z;
            }
        #pragma unroll
        for (int ks = 0; ks < 2; ++ks)
            #pragma unroll
            for (int tn = 0; tn < 4; ++tn) {
                short8 rb = *(const short8*)(rwP + ((ks * 4 + tn) * 64 + lane) * 8);
                #pragma unroll
                for (int tm = 0; tm < 2; ++tm)
                    acc[tm][tn] = __builtin_amdgcn_mfma_f32_16x16x32_bf16(afr[tm][ks], rb, acc[tm][tn], 0, 0, 0);
            }

        __builtin_amdgcn_wave_barrier();
        #pragma unroll
        for (int tm = 0; tm < 2; ++tm)
            #pragma unroll
            for (int tn = 0; tn < 4; ++tn)
                #pragma unroll
                for (int pr = 0; pr < 2; ++pr) {
                    float2v a2 = {acc[tm][tn][2 * pr], acc[tm][tn][2 * pr + 1]};
                    a2 = a2 + (float2v){hd[tn], hd[tn]};
                    a2 = __builtin_elementwise_max(a2, (float2v){0.0f, 0.0f});
                    uint32_t u = cvt_pk_bf16(a2[0], a2[1]);
                    int m0 = mbase + (ph * 2 + tm) * 16 + q * 4 + 2 * pr;
                    int i0 = m0 * 64 + c + (((tn * 2) ^ (m0 & 7)) << 3);
                    fh[i0]       = (unsigned short)u;
                    fh[i0 + d01] = (unsigned short)(u >> 16);
                }
    }

    // ---------------- scan part 2: cross-wave prefix (LDS slot read) ---------
    __syncthreads();   // orders the w1s slot writes
    float sw0 = w1s[640];
    float sw1 = w1s[641];
    float sw2 = w1s[642];
    float basev = ((wv > 0) ? sw0 : 0.0f) + ((wv > 1) ? sw1 : 0.0f)
                + ((wv > 2) ? sw2 : 0.0f);
    float excl = __shfl_up(v, 1);
    if (lane == 0) excl = 0.0f;
    float cum    = basev + excl;
    float trans  = __expf(cum);
    float weight = trans * (1.0f - __expf(av));
    bool  mask2  = maskA && (trans > 1e-4f);

    // ---------------- Phase E: final 64->3 via transposed MFMA ---------------
    float wm = mask2 ? weight : 0.0f;
    // weights for rows tn*16+c via wave shuffle (all lanes execute: sources active)
    float wgt[4];
    #pragma unroll
    for (int tn = 0; tn < 4; ++tn) wgt[tn] = __shfl(wm, tn * 16 + c, 64);

    const unsigned short* __restrict__ w2eP = (const unsigned short*)(ws + WS_W2E);
    short8 w2f[2];
    w2f[0] = *(const short8*)(w2eP + (0 * 64 + lane) * 8);
    w2f[1] = *(const short8*)(w2eP + (1 * 64 + lane) * 8);

    floatx4 eacc[4];
    #pragma unroll
    for (int tn = 0; tn < 4; ++tn) {
        floatx4 z; z[0] = 0.0f; z[1] = 0.0f; z[2] = 0.0f; z[3] = 0.0f;
        eacc[tn] = z;
    }
    #pragma unroll
    for (int kf = 0; kf < 2; ++kf)
        #pragma unroll
        for (int tn = 0; tn < 4; ++tn) {
            int m = mbase + tn * 16 + c;
            int gl = kf * 4 + q;
            short8 hb = *(const short8*)&fh[m * 64 + ((gl ^ (m & 7)) << 3)];
            eacc[tn] = __builtin_amdgcn_mfma_f32_16x16x32_bf16(w2f[kf], hb, eacc[tn], 0, 0, 0);
        }

    float r = 0.0f, g = 0.0f, b = 0.0f;
    if (q == 0) {
        float rb0 = r_b2[0], rb1 = r_b2[1], rb2v = r_b2[2];
        #pragma unroll
        for (int tn = 0; tn < 4; ++tn) {
            float wgtv = wgt[tn];
            r += wgtv / (1.0f + __expf(-(eacc[tn][0] + rb0)));
            g += wgtv / (1.0f + __expf(-(eacc[tn][1] + rb1)));
            b += wgtv / (1.0f + __expf(-(eacc[tn][2] + rb2v)));
        }
    }
    #pragma unroll
    for (int off = 8; off > 0; off >>= 1) {
        r += __shfl_xor(r, off);
        g += __shfl_xor(g, off);
        b += __shfl_xor(b, off);
    }
    // cross-wave partials via w1s (LDS), final sum by tid 0
    if (lane == 0) {
        w1s[644 + wv * 3 + 0] = r;
        w1s[644 + wv * 3 + 1] = g;
        w1s[644 + wv * 3 + 2] = b;
    }
    __syncthreads();
    if (tid == 0) {
        out[ray * 3 + 0] = w1s[644] + w1s[647] + w1s[650] + w1s[653];
        out[ray * 3 + 1] = w1s[645] + w1s[648] + w1s[651] + w1s[654];
        out[ray * 3 + 2] = w1s[646] + w1s[649] + w1s[652] + w1s[655];
    }
}

extern "C" void kernel_launch(void* const* d_in, const int* in_sizes, int n_in,
                              void* d_out, int out_size, void* d_ws, size_t ws_size,
                              hipStream_t stream) {
    const int n_rays = in_sizes[0] / 3;   // 4096
    nerf_prep<<<1, 256, 0, stream>>>(
        (const float*)d_in[3], (const float*)d_in[4], (const float*)d_in[5],
        (const float*)d_in[6], (const float*)d_in[7], (const float*)d_in[8],
        (const float*)d_in[9], (const float*)d_in[11], (unsigned char*)d_ws);
    nerf_mfma<<<n_rays, 256, 0, stream>>>(
        (const float*)d_in[0],  (const float*)d_in[1],  (const float*)d_in[2],
        (const float*)d_in[6],  (const float*)d_in[9],  (const float*)d_in[10],
        (const float*)d_in[12],
        (const unsigned char*)d_ws, (float*)d_out);
}

// Round 10
// 162.626 us; speedup vs baseline: 1.0421x; 1.0421x over previous
//
#include <hip/hip_runtime.h>
#include <hip/hip_bf16.h>
#include <math.h>
#include <stdint.h>

#define S    256
#define GN   128

typedef __attribute__((ext_vector_type(8))) short  short8;   // 8 bf16
typedef __attribute__((ext_vector_type(4))) float  floatx4;  // MFMA C/D
typedef __attribute__((ext_vector_type(2))) float  float2v;  // v_pk_*_f32 pair

// workspace layout (bytes)
#define WS_BHI 0          // ushort[4*4*64*8] = 16384 B  (f_w2 bf16, frag order)
#define WS_RW1 16384      // ushort[2*4*64*8] =  8192 B  (r_w1 bf16, frag order)
#define WS_B2S 24576      // float  (b2.s_w + s_b)
#define WS_WS2 24592      // float[128]  (W2 @ s_w, fp32)
#define WS_W1P 25104      // float[64*8] pair-interleaved layer-1 = 2048 B
#define WS_W2E 27152      // ushort[2*64*8] = 2048 B (r_w2^T bf16, A-frag order)

__device__ __forceinline__ unsigned short bf16_rtne(float f) {
    uint32_t u = __builtin_bit_cast(uint32_t, f);
    uint32_t r = (u + 0x7fffu + ((u >> 16) & 1u)) >> 16;
    return (unsigned short)r;
}
__device__ __forceinline__ uint32_t cvt_pk_bf16(float a, float b) {
    float2 hh; hh.x = a; hh.y = b;
    __hip_bfloat162 pk = __float22bfloat162_rn(hh);   // v_cvt_pk_bf16_f32
    uint32_t u; __builtin_memcpy(&u, &pk, 4);
    return u;
}

// ---------- pre-pack kernel: weights -> bf16 in MFMA fragment order ----------
__global__ __launch_bounds__(256)
void nerf_prep(const float* __restrict__ f_w1, const float* __restrict__ f_b1,
               const float* __restrict__ f_w2, const float* __restrict__ f_b2,
               const float* __restrict__ s_w,  const float* __restrict__ s_b,
               const float* __restrict__ r_w1, const float* __restrict__ r_w2,
               unsigned char* __restrict__ ws)
{
    const int tid = threadIdx.x;
    if (tid < 128) {                       // ws2 = W2 @ s_w  (fp32) -> global
        float acc = 0.0f;
        for (int n = 0; n < 64; ++n) acc += f_w2[tid * 64 + n] * s_w[n];
        ((float*)(ws + WS_WS2))[tid] = acc;
    } else if (tid == 128) {               // b2s = b2 . s_w + s_b
        float acc = s_b[0];
        for (int n = 0; n < 64; ++n) acc += f_b2[n] * s_w[n];
        *(float*)(ws + WS_B2S) = acc;
    }
    // layer-1 pair-interleaved pack: pair pp covers k=2pp,2pp+1:
    //   {wx0,wx1, wy0,wy1, wz0,wz1, b0,b1}  (aligned float2 pairs for v_pk_fma)
    {
        float* w1pk = (float*)(ws + WS_W1P);
        for (int pp = tid; pp < 64; pp += 256) {
            int k0 = 2 * pp, k1 = 2 * pp + 1;
            w1pk[pp * 8 + 0] = f_w1[k0];       w1pk[pp * 8 + 1] = f_w1[k1];
            w1pk[pp * 8 + 2] = f_w1[128 + k0]; w1pk[pp * 8 + 3] = f_w1[128 + k1];
            w1pk[pp * 8 + 4] = f_w1[256 + k0]; w1pk[pp * 8 + 5] = f_w1[256 + k1];
            w1pk[pp * 8 + 6] = f_b1[k0];       w1pk[pp * 8 + 7] = f_b1[k1];
        }
    }

    unsigned short* bhi = (unsigned short*)(ws + WS_BHI);
    for (int i = tid; i < 8192; i += 256) {
        int j = i & 7, L = (i >> 3) & 63, g = i >> 9;   // g = kc*4 + tn
        int tn = g & 3, kc = g >> 2;
        int q = L >> 4, cc = L & 15;
        int k = kc * 32 + q * 8 + j;
        bhi[i] = bf16_rtne(f_w2[k * 64 + tn * 16 + cc]);
    }
    unsigned short* rw = (unsigned short*)(ws + WS_RW1);
    for (int i = tid; i < 4096; i += 256) {
        int j = i & 7, L = (i >> 3) & 63, g = i >> 9;   // g = ks*4 + tn
        int tn = g & 3, ks = g >> 2;
        int q = L >> 4, cc = L & 15;
        int k = ks * 32 + q * 8 + j;
        rw[i] = bf16_rtne(r_w1[k * 64 + tn * 16 + cc]);
    }
    // r_w2^T in A-fragment order for the phase-E MFMA:
    // A[row=out-channel][k=hidden]; rows 3..15 zero.
    unsigned short* w2e = (unsigned short*)(ws + WS_W2E);
    for (int i = tid; i < 1024; i += 256) {
        int j = i & 7, L = (i >> 3) & 63, kf = i >> 9;
        int q = L >> 4, ch = L & 15;
        int k = kf * 32 + q * 8 + j;
        w2e[i] = (ch < 3) ? bf16_rtne(r_w2[k * 3 + ch]) : (unsigned short)0;
    }
}

// ---------------------------- main kernel -----------------------------------
// R27 = R26 (86.0 us, best verified) + s_setprio(1)/(0) around the three MFMA
// clusters (phase B kc-loop, phase D, phase E). Zero registers, zero layout
// change, zero spill risk.
// Rationale: R25 removed the mid-kernel barriers, so the block's 4 waves now
// genuinely slip into different phases -- the role-diversity regime where
// setprio has measured effect (T5: +4-7% attn; null only on barrier-lockstep
// schedules). A wave entering its MFMA burst gets issue priority over
// siblings grinding VALU glue, clearing its dependency chain sooner.
// Pre-commit: positive -> confirmed; null -> last lever exhausted, next round
// writes the structural-ceiling analysis (~49 us VALU-issue floor; all
// deeper restructures closed by the R16/R18/R20/R22 register-cliff evidence).
// Tripwires (must be UNCHANGED): VGPR 64, LDS 35840, WRITE ~1.3 MB, conf 0.
__global__ __launch_bounds__(256, 4)
void nerf_mfma(const float* __restrict__ rays_o,
               const float* __restrict__ rays_d,
               const float* __restrict__ grid,
               const float* __restrict__ f_b2,
               const float* __restrict__ r_w1,
               const float* __restrict__ r_b1,
               const float* __restrict__ r_b2,
               const unsigned char* __restrict__ ws,
               float* __restrict__ out)
{
    // fh: bf16 [256 rows][64], XOR-swizzled in 8-ushort groups: conflict-free
    // b128. Wave-private throughout.
    __shared__ __align__(16) unsigned short fh[256 * 64];
    // w1s: [0..511] layer-1 pack, [512..639] ws2, [640..643] sWaveSum,
    //      [644..655] sPart.
    __shared__ __align__(16) float w1s[656];

    const int tid   = threadIdx.x;
    const int ray   = blockIdx.x;
    const int lane  = tid & 63;
    const int wv    = tid >> 6;
    const int q     = lane >> 4;
    const int c     = lane & 15;
    const int mbase = wv * 64;
    const int d01   = 72 - ((c >> 3) << 4);   // i1 - i0 in the epilogue swizzle

    // stage layer-1 pack (2 KB) + ws2 (512 B) into dedicated LDS
    if (tid < 128) {
        ((float4*)w1s)[tid] = ((const float4*)(ws + WS_W1P))[tid];
        w1s[512 + tid]      = ((const float*)(ws + WS_WS2))[tid];
    }

    // ---------------- Phase A: geometry + grid sample (thread = sample) ------
    const float stop = 1.0f - 1.0f / (float)(S + 2);
    const float step = stop / (float)S;
    float u0 = (float)tid * step;
    float u1 = (float)(tid + 1) * step;
    float t    = (u0 < 0.5f) ? 2.0f * u0 : 1.0f / (2.0f - 2.0f * u0);
    float tn_  = (u1 < 0.5f) ? 2.0f * u1 : 1.0f / (2.0f - 2.0f * u1);
    float dist = tn_ - t;

    float ox = rays_o[ray * 3 + 0], oy = rays_o[ray * 3 + 1], oz = rays_o[ray * 3 + 2];
    float dxv = rays_d[ray * 3 + 0], dyv = rays_d[ray * 3 + 1], dzv = rays_d[ray * 3 + 2];

    float px = ox + dxv * t, py = oy + dyv * t, pz = oz + dzv * t;
    float nrm = sqrtf(px * px + py * py + pz * pz);
    float scale = (nrm <= 1.0f) ? 0.5f : (2.0f - 1.0f / nrm) / nrm * 0.5f;
    float cx = px * scale, cy = py * scale, cz = pz * scale;

    float ix = ((cx + 1.0f) * (float)GN - 1.0f) * 0.5f;
    float iy = ((cy + 1.0f) * (float)GN - 1.0f) * 0.5f;
    float iz = ((cz + 1.0f) * (float)GN - 1.0f) * 0.5f;
    float fx0 = floorf(ix), fy0 = floorf(iy), fz0 = floorf(iz);
    float fx = ix - fx0, fy = iy - fy0, fz = iz - fz0;
    int x0 = (int)fx0, y0 = (int)fy0, z0 = (int)fz0;
    int x1 = x0 + 1, y1 = y0 + 1, z1 = z0 + 1;

    // contracted coords strictly inside [-1,1] -> x0 in [-1,127], x1 in [0,128].
    // Only boundary taps can be invalid: zero the per-axis weight, clamp the
    // index. 0*g == 0 exactly; product order (wx*wy)*wz matches branchy version.
    float wxv[2], wyv[2], wzv[2];
    wxv[0] = (x0 >= 0) ? (1.0f - fx) : 0.0f;  wxv[1] = (x1 < GN) ? fx : 0.0f;
    wyv[0] = (y0 >= 0) ? (1.0f - fy) : 0.0f;  wyv[1] = (y1 < GN) ? fy : 0.0f;
    wzv[0] = (z0 >= 0) ? (1.0f - fz) : 0.0f;  wzv[1] = (z1 < GN) ? fz : 0.0f;
    int xc[2], yb[2], zb[2];
    xc[0] = (x0 < 0) ? 0 : x0;              xc[1] = (x1 > GN - 1) ? GN - 1 : x1;
    yb[0] = ((y0 < 0) ? 0 : y0) * GN;       yb[1] = ((y1 > GN - 1) ? GN - 1 : y1) * GN;
    zb[0] = ((z0 < 0) ? 0 : z0) * (GN*GN);  zb[1] = ((z1 > GN - 1) ? GN - 1 : z1) * (GN*GN);

    float occ = 0.0f;
    #pragma unroll
    for (int dzc = 0; dzc < 2; ++dzc)
    #pragma unroll
    for (int dyc = 0; dyc < 2; ++dyc)
    #pragma unroll
    for (int dxc = 0; dxc < 2; ++dxc) {
        float w = (wxv[dxc] * wyv[dyc]) * wzv[dzc];
        occ += w * grid[zb[dzc] + yb[dyc] + xc[dxc]];
    }
    bool maskA = occ > 0.01f;

    __syncthreads();   // w1s staged

    // ------- Phase B+C: feat GEMM in two tm-passes (acc[2][4] = 32 AGPR) -----
    const unsigned short* __restrict__ bhiP = (const unsigned short*)(ws + WS_BHI);
    float sgv[4] = {0.0f, 0.0f, 0.0f, 0.0f};   // all reads/writes literal-indexed

    #pragma unroll 1
    for (int ph = 0; ph < 2; ++ph) {
        // coords of the A-fragment rows for THIS pass (literal-indexed pair;
        // ph only appears in the shuffle source lane -> no scratch)
        float cxs[2], cys[2], czs[2];
        #pragma unroll
        for (int tm = 0; tm < 2; ++tm) {
            int src = (ph * 2 + tm) * 16 + c;
            cxs[tm] = __shfl(cx, src, 64);
            cys[tm] = __shfl(cy, src, 64);
            czs[tm] = __shfl(cz, src, 64);
        }

        floatx4 acc[2][4];
        {
            float b2v[4];
            #pragma unroll
            for (int tn = 0; tn < 4; ++tn) b2v[tn] = f_b2[tn * 16 + c];
            #pragma unroll
            for (int tm = 0; tm < 2; ++tm)
                #pragma unroll
                for (int tn = 0; tn < 4; ++tn) {
                    floatx4 v; v[0] = b2v[tn]; v[1] = b2v[tn]; v[2] = b2v[tn]; v[3] = b2v[tn];
                    acc[tm][tn] = v;
                }
        }
        float2v sig2[2];
        sig2[0][0] = 0.0f; sig2[0][1] = 0.0f;
        sig2[1][0] = 0.0f; sig2[1][1] = 0.0f;

        #pragma unroll 2
        for (int kc = 0; kc < 4; ++kc) {
            const int k0  = kc * 32 + q * 8;
            const int pp0 = kc * 16 + q * 4;
            const float4* w1q4 = (const float4*)&w1s[pp0 * 8];
            float ws2r[8];
            *(float4*)(ws2r)     = *(const float4*)&w1s[512 + k0];
            *(float4*)(ws2r + 4) = *(const float4*)&w1s[512 + k0 + 4];

            uint32_t packed[2][4];
            #pragma unroll
            for (int p = 0; p < 4; ++p) {
                float4 q0 = w1q4[2 * p];         // {wx0,wx1, wy0,wy1}
                float4 q1 = w1q4[2 * p + 1];     // {wz0,wz1, b0, b1}
                float2v wx2 = {q0.x, q0.y};
                float2v wy2 = {q0.z, q0.w};
                float2v wz2 = {q1.x, q1.y};
                float2v bb2 = {q1.z, q1.w};
                float2v wsp = {ws2r[2 * p], ws2r[2 * p + 1]};
                #pragma unroll
                for (int tm = 0; tm < 2; ++tm) {
                    float2v h2 = bb2;
                    h2 = __builtin_elementwise_fma((float2v){cxs[tm], cxs[tm]}, wx2, h2);
                    h2 = __builtin_elementwise_fma((float2v){cys[tm], cys[tm]}, wy2, h2);
                    h2 = __builtin_elementwise_fma((float2v){czs[tm], czs[tm]}, wz2, h2);
                    h2 = __builtin_elementwise_max(h2, (float2v){0.0f, 0.0f});
                    sig2[tm] = __builtin_elementwise_fma(h2, wsp, sig2[tm]);
                    packed[tm][p] = cvt_pk_bf16(h2[0], h2[1]);
                }
            }
            short8 Ah[2];
            #pragma unroll
            for (int tm = 0; tm < 2; ++tm) {
                uint4 v4 = {packed[tm][0], packed[tm][1], packed[tm][2], packed[tm][3]};
                Ah[tm] = __builtin_bit_cast(short8, v4);
            }
            const int bbase = (kc * 4) * 512 + lane * 8;
            __builtin_amdgcn_s_setprio(1);
            #pragma unroll
            for (int tn = 0; tn < 4; ++tn) {
                short8 bh = *(const short8*)(bhiP + bbase + tn * 512);
                #pragma unroll
                for (int tm = 0; tm < 2; ++tm)
                    acc[tm][tn] = __builtin_amdgcn_mfma_f32_16x16x32_bf16(Ah[tm], bh, acc[tm][tn], 0, 0, 0);
            }
            __builtin_amdgcn_s_setprio(0);
        }

        // NO barrier: fh is wave-private (staging lives in w1s).

        // phase C for this pass: feat rows -> fh, sigma partials collapse
        #pragma unroll
        for (int tm = 0; tm < 2; ++tm)
            #pragma unroll
            for (int tn = 0; tn < 4; ++tn)
                #pragma unroll
                for (int pr = 0; pr < 2; ++pr) {
                    uint32_t u = cvt_pk_bf16(acc[tm][tn][2 * pr], acc[tm][tn][2 * pr + 1]);
                    int m0 = mbase + (ph * 2 + tm) * 16 + q * 4 + 2 * pr;
                    int i0 = m0 * 64 + c + (((tn * 2) ^ (m0 & 7)) << 3);
                    fh[i0]       = (unsigned short)u;
                    fh[i0 + d01] = (unsigned short)(u >> 16);
                }
        {
            float s0 = sig2[0][0] + sig2[0][1];
            s0 += __shfl_xor(s0, 16);
            s0 += __shfl_xor(s0, 32);
            float s1 = sig2[1][0] + sig2[1][1];
            s1 += __shfl_xor(s1, 16);
            s1 += __shfl_xor(s1, 32);
            if (ph == 0) { sgv[0] = s0; sgv[1] = s1; }   // wave-uniform branch,
            else         { sgv[2] = s0; sgv[3] = s1; }   // literal indices
        }
    }

    // ------- per-lane sigma: sgv[] is q-broadcast; own row = lane -> sgv[q] --
    float av;
    {
        float b2s = *(const float*)(ws + WS_B2S);
        float s01  = (q & 1) ? sgv[1] : sgv[0];
        float s23  = (q & 1) ? sgv[3] : sgv[2];
        float sa = ((q & 2) ? s23 : s01) + b2s;
        float sg = maskA ? (fmaxf(sa, 0.0f) + __logf(1.0f + __expf(-fabsf(sa)))) : 0.0f;
        av = -sg * dist;
    }

    // hd[] uniform loads: latency hides under the scan below
    float hd[4];
    #pragma unroll
    for (int tn = 0; tn < 4; ++tn) {
        int n = tn * 16 + c;
        hd[tn] = r_b1[n] + dxv * r_w1[64 * 64 + n] + dyv * r_w1[65 * 64 + n] + dzv * r_w1[66 * 64 + n];
    }

    // ---------------- transmittance scan, part 1 (intra-wave) ----------------
    float v = av;
    #pragma unroll
    for (int off = 1; off < 64; off <<= 1) {
        float u2 = __shfl_up(v, off);
        if (lane >= off) v += u2;
    }
    // LDS slot-write NOW; barrier + dependent read happen AFTER phase D, so
    // even the short LDS latency hides under the rgb-hidden GEMM.
    if (lane == 63 && wv < 3) w1s[640 + wv] = v;

    // ---------------- Phase D: rgb-hidden GEMM, two tm-passes ----------------
    const unsigned short* __restrict__ rwP = (const unsigned short*)(ws + WS_RW1);

    #pragma unroll 1
    for (int ph = 0; ph < 2; ++ph) {
        // pass-0 epilogue writes rows mbase+0..31; pass-1 afr reads rows
        // mbase+32..63 -- disjoint, wave-private: no barrier needed.
        short8 afr[2][2];
        #pragma unroll
        for (int tm = 0; tm < 2; ++tm)
            #pragma unroll
            for (int ks = 0; ks < 2; ++ks) {
                int m = mbase + (ph * 2 + tm) * 16 + c;
                int gl = ks * 4 + q;
                afr[tm][ks] = *(const short8*)&fh[m * 64 + ((gl ^ (m & 7)) << 3)];
            }

        floatx4 acc[2][4];
        #pragma unroll
        for (int tm = 0; tm < 2; ++tm)
            #pragma unroll
            for (int tn = 0; tn < 4; ++tn) {
                floatx4 z; z[0] = 0.0f; z[1] = 0.0f; z[2] = 0.0f; z[3] = 0.0f;
                acc[tm][tn] = z;
            }
        __builtin_amdgcn_s_setprio(1);
        #pragma unroll
        for (int ks = 0; ks < 2; ++ks)
            #pragma unroll
            for (int tn = 0; tn < 4; ++tn) {
                short8 rb = *(const short8*)(rwP + ((ks * 4 + tn) * 64 + lane) * 8);
                #pragma unroll
                for (int tm = 0; tm < 2; ++tm)
                    acc[tm][tn] = __builtin_amdgcn_mfma_f32_16x16x32_bf16(afr[tm][ks], rb, acc[tm][tn], 0, 0, 0);
            }
        __builtin_amdgcn_s_setprio(0);

        __builtin_amdgcn_wave_barrier();
        #pragma unroll
        for (int tm = 0; tm < 2; ++tm)
            #pragma unroll
            for (int tn = 0; tn < 4; ++tn)
                #pragma unroll
                for (int pr = 0; pr < 2; ++pr) {
                    float2v a2 = {acc[tm][tn][2 * pr], acc[tm][tn][2 * pr + 1]};
                    a2 = a2 + (float2v){hd[tn], hd[tn]};
                    a2 = __builtin_elementwise_max(a2, (float2v){0.0f, 0.0f});
                    uint32_t u = cvt_pk_bf16(a2[0], a2[1]);
                    int m0 = mbase + (ph * 2 + tm) * 16 + q * 4 + 2 * pr;
                    int i0 = m0 * 64 + c + (((tn * 2) ^ (m0 & 7)) << 3);
                    fh[i0]       = (unsigned short)u;
                    fh[i0 + d01] = (unsigned short)(u >> 16);
                }
    }

    // ---------------- scan part 2: cross-wave prefix (LDS slot read) ---------
    __syncthreads();   // orders the w1s slot writes
    float sw0 = w1s[640];
    float sw1 = w1s[641];
    float sw2 = w1s[642];
    float basev = ((wv > 0) ? sw0 : 0.0f) + ((wv > 1) ? sw1 : 0.0f)
                + ((wv > 2) ? sw2 : 0.0f);
    float excl = __shfl_up(v, 1);
    if (lane == 0) excl = 0.0f;
    float cum    = basev + excl;
    float trans  = __expf(cum);
    float weight = trans * (1.0f - __expf(av));
    bool  mask2  = maskA && (trans > 1e-4f);

    // ---------------- Phase E: final 64->3 via transposed MFMA ---------------
    float wm = mask2 ? weight : 0.0f;
    // weights for rows tn*16+c via wave shuffle (all lanes execute: sources active)
    float wgt[4];
    #pragma unroll
    for (int tn = 0; tn < 4; ++tn) wgt[tn] = __shfl(wm, tn * 16 + c, 64);

    const unsigned short* __restrict__ w2eP = (const unsigned short*)(ws + WS_W2E);
    short8 w2f[2];
    w2f[0] = *(const short8*)(w2eP + (0 * 64 + lane) * 8);
    w2f[1] = *(const short8*)(w2eP + (1 * 64 + lane) * 8);

    floatx4 eacc[4];
    #pragma unroll
    for (int tn = 0; tn < 4; ++tn) {
        floatx4 z; z[0] = 0.0f; z[1] = 0.0f; z[2] = 0.0f; z[3] = 0.0f;
        eacc[tn] = z;
    }
    __builtin_amdgcn_s_setprio(1);
    #pragma unroll
    for (int kf = 0; kf < 2; ++kf)
        #pragma unroll
        for (int tn = 0; tn < 4; ++tn) {
            int m = mbase + tn * 16 + c;
            int gl = kf * 4 + q;
            short8 hb = *(const short8*)&fh[m * 64 + ((gl ^ (m & 7)) << 3)];
            eacc[tn] = __builtin_amdgcn_mfma_f32_16x16x32_bf16(w2f[kf], hb, eacc[tn], 0, 0, 0);
        }
    __builtin_amdgcn_s_setprio(0);

    float r = 0.0f, g = 0.0f, b = 0.0f;
    if (q == 0) {
        float rb0 = r_b2[0], rb1 = r_b2[1], rb2v = r_b2[2];
        #pragma unroll
        for (int tn = 0; tn < 4; ++tn) {
            float wgtv = wgt[tn];
            r += wgtv / (1.0f + __expf(-(eacc[tn][0] + rb0)));
            g += wgtv / (1.0f + __expf(-(eacc[tn][1] + rb1)));
            b += wgtv / (1.0f + __expf(-(eacc[tn][2] + rb2v)));
        }
    }
    #pragma unroll
    for (int off = 8; off > 0; off >>= 1) {
        r += __shfl_xor(r, off);
        g += __shfl_xor(g, off);
        b += __shfl_xor(b, off);
    }
    // cross-wave partials via w1s (LDS), final sum by tid 0
    if (lane == 0) {
        w1s[644 + wv * 3 + 0] = r;
        w1s[644 + wv * 3 + 1] = g;
        w1s[644 + wv * 3 + 2] = b;
    }
    __syncthreads();
    if (tid == 0) {
        out[ray * 3 + 0] = w1s[644] + w1s[647] + w1s[650] + w1s[653];
        out[ray * 3 + 1] = w1s[645] + w1s[648] + w1s[651] + w1s[654];
        out[ray * 3 + 2] = w1s[646] + w1s[649] + w1s[652] + w1s[655];
    }
}

extern "C" void kernel_launch(void* const* d_in, const int* in_sizes, int n_in,
                              void* d_out, int out_size, void* d_ws, size_t ws_size,
                              hipStream_t stream) {
    const int n_rays = in_sizes[0] / 3;   // 4096
    nerf_prep<<<1, 256, 0, stream>>>(
        (const float*)d_in[3], (const float*)d_in[4], (const float*)d_in[5],
        (const float*)d_in[6], (const float*)d_in[7], (const float*)d_in[8],
        (const float*)d_in[9], (const float*)d_in[11], (unsigned char*)d_ws);
    nerf_mfma<<<n_rays, 256, 0, stream>>>(
        (const float*)d_in[0],  (const float*)d_in[1],  (const float*)d_in[2],
        (const float*)d_in[6],  (const float*)d_in[9],  (const float*)d_in[10],
        (const float*)d_in[12],
        (const unsigned char*)d_ws, (float*)d_out);
}

// Round 11
// 162.508 us; speedup vs baseline: 1.0428x; 1.0007x over previous
//
#include <hip/hip_runtime.h>
#include <hip/hip_bf16.h>
#include <math.h>
#include <stdint.h>

#define S    256
#define GN   128

typedef __attribute__((ext_vector_type(8))) short  short8;   // 8 bf16
typedef __attribute__((ext_vector_type(4))) float  floatx4;  // MFMA C/D
typedef __attribute__((ext_vector_type(2))) float  float2v;  // v_pk_*_f32 pair

// workspace layout (bytes)
#define WS_BHI 0          // ushort[4*4*64*8] = 16384 B  (f_w2 bf16, frag order)
#define WS_RW1 16384      // ushort[2*4*64*8] =  8192 B  (r_w1 bf16, frag order)
#define WS_B2S 24576      // float  (b2.s_w + s_b)
#define WS_WS2 24592      // float[128]  (W2 @ s_w, fp32)
#define WS_W1P 25104      // float[64*8] pair-interleaved layer-1 = 2048 B
#define WS_W2E 27152      // ushort[2*64*8] = 2048 B (r_w2^T bf16, A-frag order)

__device__ __forceinline__ unsigned short bf16_rtne(float f) {
    uint32_t u = __builtin_bit_cast(uint32_t, f);
    uint32_t r = (u + 0x7fffu + ((u >> 16) & 1u)) >> 16;
    return (unsigned short)r;
}
__device__ __forceinline__ uint32_t cvt_pk_bf16(float a, float b) {
    float2 hh; hh.x = a; hh.y = b;
    __hip_bfloat162 pk = __float22bfloat162_rn(hh);   // v_cvt_pk_bf16_f32
    uint32_t u; __builtin_memcpy(&u, &pk, 4);
    return u;
}

// ---------- pre-pack kernel: weights -> bf16 in MFMA fragment order ----------
__global__ __launch_bounds__(256)
void nerf_prep(const float* __restrict__ f_w1, const float* __restrict__ f_b1,
               const float* __restrict__ f_w2, const float* __restrict__ f_b2,
               const float* __restrict__ s_w,  const float* __restrict__ s_b,
               const float* __restrict__ r_w1, const float* __restrict__ r_w2,
               unsigned char* __restrict__ ws)
{
    const int tid = threadIdx.x;
    if (tid < 128) {                       // ws2 = W2 @ s_w  (fp32) -> global
        float acc = 0.0f;
        for (int n = 0; n < 64; ++n) acc += f_w2[tid * 64 + n] * s_w[n];
        ((float*)(ws + WS_WS2))[tid] = acc;
    } else if (tid == 128) {               // b2s = b2 . s_w + s_b
        float acc = s_b[0];
        for (int n = 0; n < 64; ++n) acc += f_b2[n] * s_w[n];
        *(float*)(ws + WS_B2S) = acc;
    }
    // layer-1 pair-interleaved pack: pair pp covers k=2pp,2pp+1:
    //   {wx0,wx1, wy0,wy1, wz0,wz1, b0,b1}  (aligned float2 pairs for v_pk_fma)
    {
        float* w1pk = (float*)(ws + WS_W1P);
        for (int pp = tid; pp < 64; pp += 256) {
            int k0 = 2 * pp, k1 = 2 * pp + 1;
            w1pk[pp * 8 + 0] = f_w1[k0];       w1pk[pp * 8 + 1] = f_w1[k1];
            w1pk[pp * 8 + 2] = f_w1[128 + k0]; w1pk[pp * 8 + 3] = f_w1[128 + k1];
            w1pk[pp * 8 + 4] = f_w1[256 + k0]; w1pk[pp * 8 + 5] = f_w1[256 + k1];
            w1pk[pp * 8 + 6] = f_b1[k0];       w1pk[pp * 8 + 7] = f_b1[k1];
        }
    }

    unsigned short* bhi = (unsigned short*)(ws + WS_BHI);
    for (int i = tid; i < 8192; i += 256) {
        int j = i & 7, L = (i >> 3) & 63, g = i >> 9;   // g = kc*4 + tn
        int tn = g & 3, kc = g >> 2;
        int q = L >> 4, cc = L & 15;
        int k = kc * 32 + q * 8 + j;
        bhi[i] = bf16_rtne(f_w2[k * 64 + tn * 16 + cc]);
    }
    unsigned short* rw = (unsigned short*)(ws + WS_RW1);
    for (int i = tid; i < 4096; i += 256) {
        int j = i & 7, L = (i >> 3) & 63, g = i >> 9;   // g = ks*4 + tn
        int tn = g & 3, ks = g >> 2;
        int q = L >> 4, cc = L & 15;
        int k = ks * 32 + q * 8 + j;
        rw[i] = bf16_rtne(r_w1[k * 64 + tn * 16 + cc]);
    }
    // r_w2^T in A-fragment order for the phase-E MFMA:
    // A[row=out-channel][k=hidden]; rows 3..15 zero.
    unsigned short* w2e = (unsigned short*)(ws + WS_W2E);
    for (int i = tid; i < 1024; i += 256) {
        int j = i & 7, L = (i >> 3) & 63, kf = i >> 9;
        int q = L >> 4, ch = L & 15;
        int k = kf * 32 + q * 8 + j;
        w2e[i] = (ch < 3) ? bf16_rtne(r_w2[k * 3 + ch]) : (unsigned short)0;
    }
}

// ---------------------------- main kernel -----------------------------------
// R28 = R27 (83.8 us, best verified) + two scheduler-hint finishers (zero
// registers, zero layout, zero spill risk):
//  (1) phase-D wave_barrier between MFMA cluster and epilogue REMOVED. The
//      fence forced all 16 MFMAs before any epilogue instruction; each
//      acc[tm][tn]'s cvt_pk/ds_write depends only on its own MFMA chain, so
//      without it the compiler can overlap early accs' epilogue VALU with
//      late MFMAs (intra-wave MFMA||VALU pipe overlap -- m114 mechanism).
//      Phase B already has no such fence; phase D was the outlier. Hint-only:
//      correctness carried by register deps + lgkmcnt.
//  (2) phase-D setprio(1) window widened to open BEFORE the afr ds_reads
//      (covers afr + acc init + rb loads + MFMAs), matching the verified
//      window shape of phases B and E (both include their operand loads).
// Pre-commit: null (>=83.5) -> scheduler family exhausted, next round writes
// the structural-ceiling declaration.
// Tripwires (must be UNCHANGED): VGPR 64, LDS 35840, WRITE ~1.35 MB, conf 0.
__global__ __launch_bounds__(256, 4)
void nerf_mfma(const float* __restrict__ rays_o,
               const float* __restrict__ rays_d,
               const float* __restrict__ grid,
               const float* __restrict__ f_b2,
               const float* __restrict__ r_w1,
               const float* __restrict__ r_b1,
               const float* __restrict__ r_b2,
               const unsigned char* __restrict__ ws,
               float* __restrict__ out)
{
    // fh: bf16 [256 rows][64], XOR-swizzled in 8-ushort groups: conflict-free
    // b128. Wave-private throughout.
    __shared__ __align__(16) unsigned short fh[256 * 64];
    // w1s: [0..511] layer-1 pack, [512..639] ws2, [640..643] sWaveSum,
    //      [644..655] sPart.
    __shared__ __align__(16) float w1s[656];

    const int tid   = threadIdx.x;
    const int ray   = blockIdx.x;
    const int lane  = tid & 63;
    const int wv    = tid >> 6;
    const int q     = lane >> 4;
    const int c     = lane & 15;
    const int mbase = wv * 64;
    const int d01   = 72 - ((c >> 3) << 4);   // i1 - i0 in the epilogue swizzle

    // stage layer-1 pack (2 KB) + ws2 (512 B) into dedicated LDS
    if (tid < 128) {
        ((float4*)w1s)[tid] = ((const float4*)(ws + WS_W1P))[tid];
        w1s[512 + tid]      = ((const float*)(ws + WS_WS2))[tid];
    }

    // ---------------- Phase A: geometry + grid sample (thread = sample) ------
    const float stop = 1.0f - 1.0f / (float)(S + 2);
    const float step = stop / (float)S;
    float u0 = (float)tid * step;
    float u1 = (float)(tid + 1) * step;
    float t    = (u0 < 0.5f) ? 2.0f * u0 : 1.0f / (2.0f - 2.0f * u0);
    float tn_  = (u1 < 0.5f) ? 2.0f * u1 : 1.0f / (2.0f - 2.0f * u1);
    float dist = tn_ - t;

    float ox = rays_o[ray * 3 + 0], oy = rays_o[ray * 3 + 1], oz = rays_o[ray * 3 + 2];
    float dxv = rays_d[ray * 3 + 0], dyv = rays_d[ray * 3 + 1], dzv = rays_d[ray * 3 + 2];

    float px = ox + dxv * t, py = oy + dyv * t, pz = oz + dzv * t;
    float nrm = sqrtf(px * px + py * py + pz * pz);
    float scale = (nrm <= 1.0f) ? 0.5f : (2.0f - 1.0f / nrm) / nrm * 0.5f;
    float cx = px * scale, cy = py * scale, cz = pz * scale;

    float ix = ((cx + 1.0f) * (float)GN - 1.0f) * 0.5f;
    float iy = ((cy + 1.0f) * (float)GN - 1.0f) * 0.5f;
    float iz = ((cz + 1.0f) * (float)GN - 1.0f) * 0.5f;
    float fx0 = floorf(ix), fy0 = floorf(iy), fz0 = floorf(iz);
    float fx = ix - fx0, fy = iy - fy0, fz = iz - fz0;
    int x0 = (int)fx0, y0 = (int)fy0, z0 = (int)fz0;
    int x1 = x0 + 1, y1 = y0 + 1, z1 = z0 + 1;

    // contracted coords strictly inside [-1,1] -> x0 in [-1,127], x1 in [0,128].
    // Only boundary taps can be invalid: zero the per-axis weight, clamp the
    // index. 0*g == 0 exactly; product order (wx*wy)*wz matches branchy version.
    float wxv[2], wyv[2], wzv[2];
    wxv[0] = (x0 >= 0) ? (1.0f - fx) : 0.0f;  wxv[1] = (x1 < GN) ? fx : 0.0f;
    wyv[0] = (y0 >= 0) ? (1.0f - fy) : 0.0f;  wyv[1] = (y1 < GN) ? fy : 0.0f;
    wzv[0] = (z0 >= 0) ? (1.0f - fz) : 0.0f;  wzv[1] = (z1 < GN) ? fz : 0.0f;
    int xc[2], yb[2], zb[2];
    xc[0] = (x0 < 0) ? 0 : x0;              xc[1] = (x1 > GN - 1) ? GN - 1 : x1;
    yb[0] = ((y0 < 0) ? 0 : y0) * GN;       yb[1] = ((y1 > GN - 1) ? GN - 1 : y1) * GN;
    zb[0] = ((z0 < 0) ? 0 : z0) * (GN*GN);  zb[1] = ((z1 > GN - 1) ? GN - 1 : z1) * (GN*GN);

    float occ = 0.0f;
    #pragma unroll
    for (int dzc = 0; dzc < 2; ++dzc)
    #pragma unroll
    for (int dyc = 0; dyc < 2; ++dyc)
    #pragma unroll
    for (int dxc = 0; dxc < 2; ++dxc) {
        float w = (wxv[dxc] * wyv[dyc]) * wzv[dzc];
        occ += w * grid[zb[dzc] + yb[dyc] + xc[dxc]];
    }
    bool maskA = occ > 0.01f;

    __syncthreads();   // w1s staged

    // ------- Phase B+C: feat GEMM in two tm-passes (acc[2][4] = 32 AGPR) -----
    const unsigned short* __restrict__ bhiP = (const unsigned short*)(ws + WS_BHI);
    float sgv[4] = {0.0f, 0.0f, 0.0f, 0.0f};   // all reads/writes literal-indexed

    #pragma unroll 1
    for (int ph = 0; ph < 2; ++ph) {
        // coords of the A-fragment rows for THIS pass (literal-indexed pair;
        // ph only appears in the shuffle source lane -> no scratch)
        float cxs[2], cys[2], czs[2];
        #pragma unroll
        for (int tm = 0; tm < 2; ++tm) {
            int src = (ph * 2 + tm) * 16 + c;
            cxs[tm] = __shfl(cx, src, 64);
            cys[tm] = __shfl(cy, src, 64);
            czs[tm] = __shfl(cz, src, 64);
        }

        floatx4 acc[2][4];
        {
            float b2v[4];
            #pragma unroll
            for (int tn = 0; tn < 4; ++tn) b2v[tn] = f_b2[tn * 16 + c];
            #pragma unroll
            for (int tm = 0; tm < 2; ++tm)
                #pragma unroll
                for (int tn = 0; tn < 4; ++tn) {
                    floatx4 v; v[0] = b2v[tn]; v[1] = b2v[tn]; v[2] = b2v[tn]; v[3] = b2v[tn];
                    acc[tm][tn] = v;
                }
        }
        float2v sig2[2];
        sig2[0][0] = 0.0f; sig2[0][1] = 0.0f;
        sig2[1][0] = 0.0f; sig2[1][1] = 0.0f;

        #pragma unroll 2
        for (int kc = 0; kc < 4; ++kc) {
            const int k0  = kc * 32 + q * 8;
            const int pp0 = kc * 16 + q * 4;
            const float4* w1q4 = (const float4*)&w1s[pp0 * 8];
            float ws2r[8];
            *(float4*)(ws2r)     = *(const float4*)&w1s[512 + k0];
            *(float4*)(ws2r + 4) = *(const float4*)&w1s[512 + k0 + 4];

            uint32_t packed[2][4];
            #pragma unroll
            for (int p = 0; p < 4; ++p) {
                float4 q0 = w1q4[2 * p];         // {wx0,wx1, wy0,wy1}
                float4 q1 = w1q4[2 * p + 1];     // {wz0,wz1, b0, b1}
                float2v wx2 = {q0.x, q0.y};
                float2v wy2 = {q0.z, q0.w};
                float2v wz2 = {q1.x, q1.y};
                float2v bb2 = {q1.z, q1.w};
                float2v wsp = {ws2r[2 * p], ws2r[2 * p + 1]};
                #pragma unroll
                for (int tm = 0; tm < 2; ++tm) {
                    float2v h2 = bb2;
                    h2 = __builtin_elementwise_fma((float2v){cxs[tm], cxs[tm]}, wx2, h2);
                    h2 = __builtin_elementwise_fma((float2v){cys[tm], cys[tm]}, wy2, h2);
                    h2 = __builtin_elementwise_fma((float2v){czs[tm], czs[tm]}, wz2, h2);
                    h2 = __builtin_elementwise_max(h2, (float2v){0.0f, 0.0f});
                    sig2[tm] = __builtin_elementwise_fma(h2, wsp, sig2[tm]);
                    packed[tm][p] = cvt_pk_bf16(h2[0], h2[1]);
                }
            }
            short8 Ah[2];
            #pragma unroll
            for (int tm = 0; tm < 2; ++tm) {
                uint4 v4 = {packed[tm][0], packed[tm][1], packed[tm][2], packed[tm][3]};
                Ah[tm] = __builtin_bit_cast(short8, v4);
            }
            const int bbase = (kc * 4) * 512 + lane * 8;
            __builtin_amdgcn_s_setprio(1);
            #pragma unroll
            for (int tn = 0; tn < 4; ++tn) {
                short8 bh = *(const short8*)(bhiP + bbase + tn * 512);
                #pragma unroll
                for (int tm = 0; tm < 2; ++tm)
                    acc[tm][tn] = __builtin_amdgcn_mfma_f32_16x16x32_bf16(Ah[tm], bh, acc[tm][tn], 0, 0, 0);
            }
            __builtin_amdgcn_s_setprio(0);
        }

        // NO barrier: fh is wave-private (staging lives in w1s).

        // phase C for this pass: feat rows -> fh, sigma partials collapse
        #pragma unroll
        for (int tm = 0; tm < 2; ++tm)
            #pragma unroll
            for (int tn = 0; tn < 4; ++tn)
                #pragma unroll
                for (int pr = 0; pr < 2; ++pr) {
                    uint32_t u = cvt_pk_bf16(acc[tm][tn][2 * pr], acc[tm][tn][2 * pr + 1]);
                    int m0 = mbase + (ph * 2 + tm) * 16 + q * 4 + 2 * pr;
                    int i0 = m0 * 64 + c + (((tn * 2) ^ (m0 & 7)) << 3);
                    fh[i0]       = (unsigned short)u;
                    fh[i0 + d01] = (unsigned short)(u >> 16);
                }
        {
            float s0 = sig2[0][0] + sig2[0][1];
            s0 += __shfl_xor(s0, 16);
            s0 += __shfl_xor(s0, 32);
            float s1 = sig2[1][0] + sig2[1][1];
            s1 += __shfl_xor(s1, 16);
            s1 += __shfl_xor(s1, 32);
            if (ph == 0) { sgv[0] = s0; sgv[1] = s1; }   // wave-uniform branch,
            else         { sgv[2] = s0; sgv[3] = s1; }   // literal indices
        }
    }

    // ------- per-lane sigma: sgv[] is q-broadcast; own row = lane -> sgv[q] --
    float av;
    {
        float b2s = *(const float*)(ws + WS_B2S);
        float s01  = (q & 1) ? sgv[1] : sgv[0];
        float s23  = (q & 1) ? sgv[3] : sgv[2];
        float sa = ((q & 2) ? s23 : s01) + b2s;
        float sg = maskA ? (fmaxf(sa, 0.0f) + __logf(1.0f + __expf(-fabsf(sa)))) : 0.0f;
        av = -sg * dist;
    }

    // hd[] uniform loads: latency hides under the scan below
    float hd[4];
    #pragma unroll
    for (int tn = 0; tn < 4; ++tn) {
        int n = tn * 16 + c;
        hd[tn] = r_b1[n] + dxv * r_w1[64 * 64 + n] + dyv * r_w1[65 * 64 + n] + dzv * r_w1[66 * 64 + n];
    }

    // ---------------- transmittance scan, part 1 (intra-wave) ----------------
    float v = av;
    #pragma unroll
    for (int off = 1; off < 64; off <<= 1) {
        float u2 = __shfl_up(v, off);
        if (lane >= off) v += u2;
    }
    // LDS slot-write NOW; barrier + dependent read happen AFTER phase D, so
    // even the short LDS latency hides under the rgb-hidden GEMM.
    if (lane == 63 && wv < 3) w1s[640 + wv] = v;

    // ---------------- Phase D: rgb-hidden GEMM, two tm-passes ----------------
    const unsigned short* __restrict__ rwP = (const unsigned short*)(ws + WS_RW1);

    #pragma unroll 1
    for (int ph = 0; ph < 2; ++ph) {
        // setprio window opens BEFORE the operand loads (matches phase B/E
        // window shape): afr ds_reads + rb loads are the MFMA critical path.
        __builtin_amdgcn_s_setprio(1);

        // pass-0 epilogue writes rows mbase+0..31; pass-1 afr reads rows
        // mbase+32..63 -- disjoint, wave-private: no barrier needed.
        short8 afr[2][2];
        #pragma unroll
        for (int tm = 0; tm < 2; ++tm)
            #pragma unroll
            for (int ks = 0; ks < 2; ++ks) {
                int m = mbase + (ph * 2 + tm) * 16 + c;
                int gl = ks * 4 + q;
                afr[tm][ks] = *(const short8*)&fh[m * 64 + ((gl ^ (m & 7)) << 3)];
            }

        floatx4 acc[2][4];
        #pragma unroll
        for (int tm = 0; tm < 2; ++tm)
            #pragma unroll
            for (int tn = 0; tn < 4; ++tn) {
                floatx4 z; z[0] = 0.0f; z[1] = 0.0f; z[2] = 0.0f; z[3] = 0.0f;
                acc[tm][tn] = z;
            }
        #pragma unroll
        for (int ks = 0; ks < 2; ++ks)
            #pragma unroll
            for (int tn = 0; tn < 4; ++tn) {
                short8 rb = *(const short8*)(rwP + ((ks * 4 + tn) * 64 + lane) * 8);
                #pragma unroll
                for (int tm = 0; tm < 2; ++tm)
                    acc[tm][tn] = __builtin_amdgcn_mfma_f32_16x16x32_bf16(afr[tm][ks], rb, acc[tm][tn], 0, 0, 0);
            }
        __builtin_amdgcn_s_setprio(0);

        // NO wave_barrier: each acc's epilogue depends only on its own MFMA
        // chain -- let the compiler overlap early accs' cvt_pk/ds_write with
        // late MFMAs (intra-wave MFMA||VALU pipe overlap).
        #pragma unroll
        for (int tm = 0; tm < 2; ++tm)
            #pragma unroll
            for (int tn = 0; tn < 4; ++tn)
                #pragma unroll
                for (int pr = 0; pr < 2; ++pr) {
                    float2v a2 = {acc[tm][tn][2 * pr], acc[tm][tn][2 * pr + 1]};
                    a2 = a2 + (float2v){hd[tn], hd[tn]};
                    a2 = __builtin_elementwise_max(a2, (float2v){0.0f, 0.0f});
                    uint32_t u = cvt_pk_bf16(a2[0], a2[1]);
                    int m0 = mbase + (ph * 2 + tm) * 16 + q * 4 + 2 * pr;
                    int i0 = m0 * 64 + c + (((tn * 2) ^ (m0 & 7)) << 3);
                    fh[i0]       = (unsigned short)u;
                    fh[i0 + d01] = (unsigned short)(u >> 16);
                }
    }

    // ---------------- scan part 2: cross-wave prefix (LDS slot read) ---------
    __syncthreads();   // orders the w1s slot writes
    float sw0 = w1s[640];
    float sw1 = w1s[641];
    float sw2 = w1s[642];
    float basev = ((wv > 0) ? sw0 : 0.0f) + ((wv > 1) ? sw1 : 0.0f)
                + ((wv > 2) ? sw2 : 0.0f);
    float excl = __shfl_up(v, 1);
    if (lane == 0) excl = 0.0f;
    float cum    = basev + excl;
    float trans  = __expf(cum);
    float weight = trans * (1.0f - __expf(av));
    bool  mask2  = maskA && (trans > 1e-4f);

    // ---------------- Phase E: final 64->3 via transposed MFMA ---------------
    float wm = mask2 ? weight : 0.0f;
    // weights for rows tn*16+c via wave shuffle (all lanes execute: sources active)
    float wgt[4];
    #pragma unroll
    for (int tn = 0; tn < 4; ++tn) wgt[tn] = __shfl(wm, tn * 16 + c, 64);

    const unsigned short* __restrict__ w2eP = (const unsigned short*)(ws + WS_W2E);
    short8 w2f[2];
    w2f[0] = *(const short8*)(w2eP + (0 * 64 + lane) * 8);
    w2f[1] = *(const short8*)(w2eP + (1 * 64 + lane) * 8);

    floatx4 eacc[4];
    #pragma unroll
    for (int tn = 0; tn < 4; ++tn) {
        floatx4 z; z[0] = 0.0f; z[1] = 0.0f; z[2] = 0.0f; z[3] = 0.0f;
        eacc[tn] = z;
    }
    __builtin_amdgcn_s_setprio(1);
    #pragma unroll
    for (int kf = 0; kf < 2; ++kf)
        #pragma unroll
        for (int tn = 0; tn < 4; ++tn) {
            int m = mbase + tn * 16 + c;
            int gl = kf * 4 + q;
            short8 hb = *(const short8*)&fh[m * 64 + ((gl ^ (m & 7)) << 3)];
            eacc[tn] = __builtin_amdgcn_mfma_f32_16x16x32_bf16(w2f[kf], hb, eacc[tn], 0, 0, 0);
        }
    __builtin_amdgcn_s_setprio(0);

    float r = 0.0f, g = 0.0f, b = 0.0f;
    if (q == 0) {
        float rb0 = r_b2[0], rb1 = r_b2[1], rb2v = r_b2[2];
        #pragma unroll
        for (int tn = 0; tn < 4; ++tn) {
            float wgtv = wgt[tn];
            r += wgtv / (1.0f + __expf(-(eacc[tn][0] + rb0)));
            g += wgtv / (1.0f + __expf(-(eacc[tn][1] + rb1)));
            b += wgtv / (1.0f + __expf(-(eacc[tn][2] + rb2v)));
        }
    }
    #pragma unroll
    for (int off = 8; off > 0; off >>= 1) {
        r += __shfl_xor(r, off);
        g += __shfl_xor(g, off);
        b += __shfl_xor(b, off);
    }
    // cross-wave partials via w1s (LDS), final sum by tid 0
    if (lane == 0) {
        w1s[644 + wv * 3 + 0] = r;
        w1s[644 + wv * 3 + 1] = g;
        w1s[644 + wv * 3 + 2] = b;
    }
    __syncthreads();
    if (tid == 0) {
        out[ray * 3 + 0] = w1s[644] + w1s[647] + w1s[650] + w1s[653];
        out[ray * 3 + 1] = w1s[645] + w1s[648] + w1s[651] + w1s[654];
        out[ray * 3 + 2] = w1s[646] + w1s[649] + w1s[652] + w1s[655];
    }
}

extern "C" void kernel_launch(void* const* d_in, const int* in_sizes, int n_in,
                              void* d_out, int out_size, void* d_ws, size_t ws_size,
                              hipStream_t stream) {
    const int n_rays = in_sizes[0] / 3;   // 4096
    nerf_prep<<<1, 256, 0, stream>>>(
        (const float*)d_in[3], (const float*)d_in[4], (const float*)d_in[5],
        (const float*)d_in[6], (const float*)d_in[7], (const float*)d_in[8],
        (const float*)d_in[9], (const float*)d_in[11], (unsigned char*)d_ws);
    nerf_mfma<<<n_rays, 256, 0, stream>>>(
        (const float*)d_in[0],  (const float*)d_in[1],  (const float*)d_in[2],
        (const float*)d_in[6],  (const float*)d_in[9],  (const float*)d_in[10],
        (const float*)d_in[12],
        (const unsigned char*)d_ws, (float*)d_out);
}

// Round 12
// 158.166 us; speedup vs baseline: 1.0715x; 1.0275x over previous
//
#include <hip/hip_runtime.h>
#include <hip/hip_bf16.h>
#include <math.h>
#include <stdint.h>

#define S    256
#define GN   128

typedef __attribute__((ext_vector_type(8))) short  short8;   // 8 bf16
typedef __attribute__((ext_vector_type(4))) float  floatx4;  // MFMA C/D
typedef __attribute__((ext_vector_type(2))) float  float2v;  // v_pk_*_f32 pair

// workspace layout (bytes)
#define WS_BHI 0          // ushort[4*4*64*8] = 16384 B  (f_w2 bf16, frag order)
#define WS_RW1 16384      // ushort[2*4*64*8] =  8192 B  (r_w1 bf16, frag order)
#define WS_B2S 24576      // float  (b2.s_w + s_b)
#define WS_WS2 24592      // float[128]  (W2 @ s_w, fp32)
#define WS_W1P 25104      // float[64*8] pair-interleaved layer-1 = 2048 B
#define WS_W2E 27152      // ushort[2*64*8] = 2048 B (r_w2^T bf16, A-frag order)

__device__ __forceinline__ unsigned short bf16_rtne(float f) {
    uint32_t u = __builtin_bit_cast(uint32_t, f);
    uint32_t r = (u + 0x7fffu + ((u >> 16) & 1u)) >> 16;
    return (unsigned short)r;
}
__device__ __forceinline__ uint32_t cvt_pk_bf16(float a, float b) {
    float2 hh; hh.x = a; hh.y = b;
    __hip_bfloat162 pk = __float22bfloat162_rn(hh);   // v_cvt_pk_bf16_f32
    uint32_t u; __builtin_memcpy(&u, &pk, 4);
    return u;
}

// ---------- pre-pack kernel: weights -> bf16 in MFMA fragment order ----------
// R29: parallelized across 32 blocks (was <<<1,256>>> -- one CU doing 13.3k
// gather+convert elements serially, ~10+ us on the bench critical path every
// iteration). Big loops are grid-strided (bhi: exactly 1 elem/thread at 32
// blocks); small ws2/b2s/w1pk packs stay on block 0. All ws regions disjoint.
__global__ __launch_bounds__(256)
void nerf_prep(const float* __restrict__ f_w1, const float* __restrict__ f_b1,
               const float* __restrict__ f_w2, const float* __restrict__ f_b2,
               const float* __restrict__ s_w,  const float* __restrict__ s_b,
               const float* __restrict__ r_w1, const float* __restrict__ r_w2,
               unsigned char* __restrict__ ws)
{
    const int tid  = threadIdx.x;
    const int gid  = blockIdx.x * 256 + tid;
    const int nthr = gridDim.x * 256;

    if (blockIdx.x == 0) {
        if (tid < 128) {                       // ws2 = W2 @ s_w  (fp32) -> global
            float acc = 0.0f;
            for (int n = 0; n < 64; ++n) acc += f_w2[tid * 64 + n] * s_w[n];
            ((float*)(ws + WS_WS2))[tid] = acc;
        } else if (tid == 128) {               // b2s = b2 . s_w + s_b
            float acc = s_b[0];
            for (int n = 0; n < 64; ++n) acc += f_b2[n] * s_w[n];
            *(float*)(ws + WS_B2S) = acc;
        }
        // layer-1 pair-interleaved pack: pair pp covers k=2pp,2pp+1:
        //   {wx0,wx1, wy0,wy1, wz0,wz1, b0,b1}
        float* w1pk = (float*)(ws + WS_W1P);
        for (int pp = tid; pp < 64; pp += 256) {
            int k0 = 2 * pp, k1 = 2 * pp + 1;
            w1pk[pp * 8 + 0] = f_w1[k0];       w1pk[pp * 8 + 1] = f_w1[k1];
            w1pk[pp * 8 + 2] = f_w1[128 + k0]; w1pk[pp * 8 + 3] = f_w1[128 + k1];
            w1pk[pp * 8 + 4] = f_w1[256 + k0]; w1pk[pp * 8 + 5] = f_w1[256 + k1];
            w1pk[pp * 8 + 6] = f_b1[k0];       w1pk[pp * 8 + 7] = f_b1[k1];
        }
    }

    unsigned short* bhi = (unsigned short*)(ws + WS_BHI);
    for (int i = gid; i < 8192; i += nthr) {
        int j = i & 7, L = (i >> 3) & 63, g = i >> 9;   // g = kc*4 + tn
        int tn = g & 3, kc = g >> 2;
        int q = L >> 4, cc = L & 15;
        int k = kc * 32 + q * 8 + j;
        bhi[i] = bf16_rtne(f_w2[k * 64 + tn * 16 + cc]);
    }
    unsigned short* rw = (unsigned short*)(ws + WS_RW1);
    for (int i = gid; i < 4096; i += nthr) {
        int j = i & 7, L = (i >> 3) & 63, g = i >> 9;   // g = ks*4 + tn
        int tn = g & 3, ks = g >> 2;
        int q = L >> 4, cc = L & 15;
        int k = ks * 32 + q * 8 + j;
        rw[i] = bf16_rtne(r_w1[k * 64 + tn * 16 + cc]);
    }
    // r_w2^T in A-fragment order for the phase-E MFMA:
    // A[row=out-channel][k=hidden]; rows 3..15 zero.
    unsigned short* w2e = (unsigned short*)(ws + WS_W2E);
    for (int i = gid; i < 1024; i += nthr) {
        int j = i & 7, L = (i >> 3) & 63, kf = i >> 9;
        int q = L >> 4, ch = L & 15;
        int k = kf * 32 + q * 8 + j;
        w2e[i] = (ch < 3) ? bf16_rtne(r_w2[k * 3 + ch]) : (unsigned short)0;
    }
}

// ---------------------------- main kernel -----------------------------------
// R29 main kernel = R28 VERBATIM (79.4 us, best verified). This round's only
// change is nerf_prep parallelization -- orthogonal observables: nerf_mfma
// dispatch dur is the tripwire (must stay 79.3-79.7), bench dur minus kernel
// dur measures the prep win.
// R28 history: removed phase-D wave_barrier (MFMA||VALU epilogue overlap) +
// widened phase-D setprio window -> 83.8 -> 79.4. R27: setprio on MFMA
// clusters (+2.6%). R26: scan via LDS slots (+2.3%). R25: dedicated w1s, no
// mid-phase-B barrier. Spill tripwires: VGPR 64, LDS 35840, WRITE ~1.3 MB.
__global__ __launch_bounds__(256, 4)
void nerf_mfma(const float* __restrict__ rays_o,
               const float* __restrict__ rays_d,
               const float* __restrict__ grid,
               const float* __restrict__ f_b2,
               const float* __restrict__ r_w1,
               const float* __restrict__ r_b1,
               const float* __restrict__ r_b2,
               const unsigned char* __restrict__ ws,
               float* __restrict__ out)
{
    // fh: bf16 [256 rows][64], XOR-swizzled in 8-ushort groups: conflict-free
    // b128. Wave-private throughout.
    __shared__ __align__(16) unsigned short fh[256 * 64];
    // w1s: [0..511] layer-1 pack, [512..639] ws2, [640..643] sWaveSum,
    //      [644..655] sPart.
    __shared__ __align__(16) float w1s[656];

    const int tid   = threadIdx.x;
    const int ray   = blockIdx.x;
    const int lane  = tid & 63;
    const int wv    = tid >> 6;
    const int q     = lane >> 4;
    const int c     = lane & 15;
    const int mbase = wv * 64;
    const int d01   = 72 - ((c >> 3) << 4);   // i1 - i0 in the epilogue swizzle

    // stage layer-1 pack (2 KB) + ws2 (512 B) into dedicated LDS
    if (tid < 128) {
        ((float4*)w1s)[tid] = ((const float4*)(ws + WS_W1P))[tid];
        w1s[512 + tid]      = ((const float*)(ws + WS_WS2))[tid];
    }

    // ---------------- Phase A: geometry + grid sample (thread = sample) ------
    const float stop = 1.0f - 1.0f / (float)(S + 2);
    const float step = stop / (float)S;
    float u0 = (float)tid * step;
    float u1 = (float)(tid + 1) * step;
    float t    = (u0 < 0.5f) ? 2.0f * u0 : 1.0f / (2.0f - 2.0f * u0);
    float tn_  = (u1 < 0.5f) ? 2.0f * u1 : 1.0f / (2.0f - 2.0f * u1);
    float dist = tn_ - t;

    float ox = rays_o[ray * 3 + 0], oy = rays_o[ray * 3 + 1], oz = rays_o[ray * 3 + 2];
    float dxv = rays_d[ray * 3 + 0], dyv = rays_d[ray * 3 + 1], dzv = rays_d[ray * 3 + 2];

    float px = ox + dxv * t, py = oy + dyv * t, pz = oz + dzv * t;
    float nrm = sqrtf(px * px + py * py + pz * pz);
    float scale = (nrm <= 1.0f) ? 0.5f : (2.0f - 1.0f / nrm) / nrm * 0.5f;
    float cx = px * scale, cy = py * scale, cz = pz * scale;

    float ix = ((cx + 1.0f) * (float)GN - 1.0f) * 0.5f;
    float iy = ((cy + 1.0f) * (float)GN - 1.0f) * 0.5f;
    float iz = ((cz + 1.0f) * (float)GN - 1.0f) * 0.5f;
    float fx0 = floorf(ix), fy0 = floorf(iy), fz0 = floorf(iz);
    float fx = ix - fx0, fy = iy - fy0, fz = iz - fz0;
    int x0 = (int)fx0, y0 = (int)fy0, z0 = (int)fz0;
    int x1 = x0 + 1, y1 = y0 + 1, z1 = z0 + 1;

    // contracted coords strictly inside [-1,1] -> x0 in [-1,127], x1 in [0,128].
    // Only boundary taps can be invalid: zero the per-axis weight, clamp the
    // index. 0*g == 0 exactly; product order (wx*wy)*wz matches branchy version.
    float wxv[2], wyv[2], wzv[2];
    wxv[0] = (x0 >= 0) ? (1.0f - fx) : 0.0f;  wxv[1] = (x1 < GN) ? fx : 0.0f;
    wyv[0] = (y0 >= 0) ? (1.0f - fy) : 0.0f;  wyv[1] = (y1 < GN) ? fy : 0.0f;
    wzv[0] = (z0 >= 0) ? (1.0f - fz) : 0.0f;  wzv[1] = (z1 < GN) ? fz : 0.0f;
    int xc[2], yb[2], zb[2];
    xc[0] = (x0 < 0) ? 0 : x0;              xc[1] = (x1 > GN - 1) ? GN - 1 : x1;
    yb[0] = ((y0 < 0) ? 0 : y0) * GN;       yb[1] = ((y1 > GN - 1) ? GN - 1 : y1) * GN;
    zb[0] = ((z0 < 0) ? 0 : z0) * (GN*GN);  zb[1] = ((z1 > GN - 1) ? GN - 1 : z1) * (GN*GN);

    float occ = 0.0f;
    #pragma unroll
    for (int dzc = 0; dzc < 2; ++dzc)
    #pragma unroll
    for (int dyc = 0; dyc < 2; ++dyc)
    #pragma unroll
    for (int dxc = 0; dxc < 2; ++dxc) {
        float w = (wxv[dxc] * wyv[dyc]) * wzv[dzc];
        occ += w * grid[zb[dzc] + yb[dyc] + xc[dxc]];
    }
    bool maskA = occ > 0.01f;

    __syncthreads();   // w1s staged

    // ------- Phase B+C: feat GEMM in two tm-passes (acc[2][4] = 32 AGPR) -----
    const unsigned short* __restrict__ bhiP = (const unsigned short*)(ws + WS_BHI);
    float sgv[4] = {0.0f, 0.0f, 0.0f, 0.0f};   // all reads/writes literal-indexed

    #pragma unroll 1
    for (int ph = 0; ph < 2; ++ph) {
        // coords of the A-fragment rows for THIS pass (literal-indexed pair;
        // ph only appears in the shuffle source lane -> no scratch)
        float cxs[2], cys[2], czs[2];
        #pragma unroll
        for (int tm = 0; tm < 2; ++tm) {
            int src = (ph * 2 + tm) * 16 + c;
            cxs[tm] = __shfl(cx, src, 64);
            cys[tm] = __shfl(cy, src, 64);
            czs[tm] = __shfl(cz, src, 64);
        }

        floatx4 acc[2][4];
        {
            float b2v[4];
            #pragma unroll
            for (int tn = 0; tn < 4; ++tn) b2v[tn] = f_b2[tn * 16 + c];
            #pragma unroll
            for (int tm = 0; tm < 2; ++tm)
                #pragma unroll
                for (int tn = 0; tn < 4; ++tn) {
                    floatx4 v; v[0] = b2v[tn]; v[1] = b2v[tn]; v[2] = b2v[tn]; v[3] = b2v[tn];
                    acc[tm][tn] = v;
                }
        }
        float2v sig2[2];
        sig2[0][0] = 0.0f; sig2[0][1] = 0.0f;
        sig2[1][0] = 0.0f; sig2[1][1] = 0.0f;

        #pragma unroll 2
        for (int kc = 0; kc < 4; ++kc) {
            const int k0  = kc * 32 + q * 8;
            const int pp0 = kc * 16 + q * 4;
            const float4* w1q4 = (const float4*)&w1s[pp0 * 8];
            float ws2r[8];
            *(float4*)(ws2r)     = *(const float4*)&w1s[512 + k0];
            *(float4*)(ws2r + 4) = *(const float4*)&w1s[512 + k0 + 4];

            uint32_t packed[2][4];
            #pragma unroll
            for (int p = 0; p < 4; ++p) {
                float4 q0 = w1q4[2 * p];         // {wx0,wx1, wy0,wy1}
                float4 q1 = w1q4[2 * p + 1];     // {wz0,wz1, b0, b1}
                float2v wx2 = {q0.x, q0.y};
                float2v wy2 = {q0.z, q0.w};
                float2v wz2 = {q1.x, q1.y};
                float2v bb2 = {q1.z, q1.w};
                float2v wsp = {ws2r[2 * p], ws2r[2 * p + 1]};
                #pragma unroll
                for (int tm = 0; tm < 2; ++tm) {
                    float2v h2 = bb2;
                    h2 = __builtin_elementwise_fma((float2v){cxs[tm], cxs[tm]}, wx2, h2);
                    h2 = __builtin_elementwise_fma((float2v){cys[tm], cys[tm]}, wy2, h2);
                    h2 = __builtin_elementwise_fma((float2v){czs[tm], czs[tm]}, wz2, h2);
                    h2 = __builtin_elementwise_max(h2, (float2v){0.0f, 0.0f});
                    sig2[tm] = __builtin_elementwise_fma(h2, wsp, sig2[tm]);
                    packed[tm][p] = cvt_pk_bf16(h2[0], h2[1]);
                }
            }
            short8 Ah[2];
            #pragma unroll
            for (int tm = 0; tm < 2; ++tm) {
                uint4 v4 = {packed[tm][0], packed[tm][1], packed[tm][2], packed[tm][3]};
                Ah[tm] = __builtin_bit_cast(short8, v4);
            }
            const int bbase = (kc * 4) * 512 + lane * 8;
            __builtin_amdgcn_s_setprio(1);
            #pragma unroll
            for (int tn = 0; tn < 4; ++tn) {
                short8 bh = *(const short8*)(bhiP + bbase + tn * 512);
                #pragma unroll
                for (int tm = 0; tm < 2; ++tm)
                    acc[tm][tn] = __builtin_amdgcn_mfma_f32_16x16x32_bf16(Ah[tm], bh, acc[tm][tn], 0, 0, 0);
            }
            __builtin_amdgcn_s_setprio(0);
        }

        // NO barrier: fh is wave-private (staging lives in w1s).

        // phase C for this pass: feat rows -> fh, sigma partials collapse
        #pragma unroll
        for (int tm = 0; tm < 2; ++tm)
            #pragma unroll
            for (int tn = 0; tn < 4; ++tn)
                #pragma unroll
                for (int pr = 0; pr < 2; ++pr) {
                    uint32_t u = cvt_pk_bf16(acc[tm][tn][2 * pr], acc[tm][tn][2 * pr + 1]);
                    int m0 = mbase + (ph * 2 + tm) * 16 + q * 4 + 2 * pr;
                    int i0 = m0 * 64 + c + (((tn * 2) ^ (m0 & 7)) << 3);
                    fh[i0]       = (unsigned short)u;
                    fh[i0 + d01] = (unsigned short)(u >> 16);
                }
        {
            float s0 = sig2[0][0] + sig2[0][1];
            s0 += __shfl_xor(s0, 16);
            s0 += __shfl_xor(s0, 32);
            float s1 = sig2[1][0] + sig2[1][1];
            s1 += __shfl_xor(s1, 16);
            s1 += __shfl_xor(s1, 32);
            if (ph == 0) { sgv[0] = s0; sgv[1] = s1; }   // wave-uniform branch,
            else         { sgv[2] = s0; sgv[3] = s1; }   // literal indices
        }
    }

    // ------- per-lane sigma: sgv[] is q-broadcast; own row = lane -> sgv[q] --
    float av;
    {
        float b2s = *(const float*)(ws + WS_B2S);
        float s01  = (q & 1) ? sgv[1] : sgv[0];
        float s23  = (q & 1) ? sgv[3] : sgv[2];
        float sa = ((q & 2) ? s23 : s01) + b2s;
        float sg = maskA ? (fmaxf(sa, 0.0f) + __logf(1.0f + __expf(-fabsf(sa)))) : 0.0f;
        av = -sg * dist;
    }

    // hd[] uniform loads: latency hides under the scan below
    float hd[4];
    #pragma unroll
    for (int tn = 0; tn < 4; ++tn) {
        int n = tn * 16 + c;
        hd[tn] = r_b1[n] + dxv * r_w1[64 * 64 + n] + dyv * r_w1[65 * 64 + n] + dzv * r_w1[66 * 64 + n];
    }

    // ---------------- transmittance scan, part 1 (intra-wave) ----------------
    float v = av;
    #pragma unroll
    for (int off = 1; off < 64; off <<= 1) {
        float u2 = __shfl_up(v, off);
        if (lane >= off) v += u2;
    }
    // LDS slot-write NOW; barrier + dependent read happen AFTER phase D, so
    // even the short LDS latency hides under the rgb-hidden GEMM.
    if (lane == 63 && wv < 3) w1s[640 + wv] = v;

    // ---------------- Phase D: rgb-hidden GEMM, two tm-passes ----------------
    const unsigned short* __restrict__ rwP = (const unsigned short*)(ws + WS_RW1);

    #pragma unroll 1
    for (int ph = 0; ph < 2; ++ph) {
        // setprio window opens BEFORE the operand loads (matches phase B/E
        // window shape): afr ds_reads + rb loads are the MFMA critical path.
        __builtin_amdgcn_s_setprio(1);

        // pass-0 epilogue writes rows mbase+0..31; pass-1 afr reads rows
        // mbase+32..63 -- disjoint, wave-private: no barrier needed.
        short8 afr[2][2];
        #pragma unroll
        for (int tm = 0; tm < 2; ++tm)
            #pragma unroll
            for (int ks = 0; ks < 2; ++ks) {
                int m = mbase + (ph * 2 + tm) * 16 + c;
                int gl = ks * 4 + q;
                afr[tm][ks] = *(const short8*)&fh[m * 64 + ((gl ^ (m & 7)) << 3)];
            }

        floatx4 acc[2][4];
        #pragma unroll
        for (int tm = 0; tm < 2; ++tm)
            #pragma unroll
            for (int tn = 0; tn < 4; ++tn) {
                floatx4 z; z[0] = 0.0f; z[1] = 0.0f; z[2] = 0.0f; z[3] = 0.0f;
                acc[tm][tn] = z;
            }
        #pragma unroll
        for (int ks = 0; ks < 2; ++ks)
            #pragma unroll
            for (int tn = 0; tn < 4; ++tn) {
                short8 rb = *(const short8*)(rwP + ((ks * 4 + tn) * 64 + lane) * 8);
                #pragma unroll
                for (int tm = 0; tm < 2; ++tm)
                    acc[tm][tn] = __builtin_amdgcn_mfma_f32_16x16x32_bf16(afr[tm][ks], rb, acc[tm][tn], 0, 0, 0);
            }
        __builtin_amdgcn_s_setprio(0);

        // NO wave_barrier: each acc's epilogue depends only on its own MFMA
        // chain -- let the compiler overlap early accs' cvt_pk/ds_write with
        // late MFMAs (intra-wave MFMA||VALU pipe overlap).
        #pragma unroll
        for (int tm = 0; tm < 2; ++tm)
            #pragma unroll
            for (int tn = 0; tn < 4; ++tn)
                #pragma unroll
                for (int pr = 0; pr < 2; ++pr) {
                    float2v a2 = {acc[tm][tn][2 * pr], acc[tm][tn][2 * pr + 1]};
                    a2 = a2 + (float2v){hd[tn], hd[tn]};
                    a2 = __builtin_elementwise_max(a2, (float2v){0.0f, 0.0f});
                    uint32_t u = cvt_pk_bf16(a2[0], a2[1]);
                    int m0 = mbase + (ph * 2 + tm) * 16 + q * 4 + 2 * pr;
                    int i0 = m0 * 64 + c + (((tn * 2) ^ (m0 & 7)) << 3);
                    fh[i0]       = (unsigned short)u;
                    fh[i0 + d01] = (unsigned short)(u >> 16);
                }
    }

    // ---------------- scan part 2: cross-wave prefix (LDS slot read) ---------
    __syncthreads();   // orders the w1s slot writes
    float sw0 = w1s[640];
    float sw1 = w1s[641];
    float sw2 = w1s[642];
    float basev = ((wv > 0) ? sw0 : 0.0f) + ((wv > 1) ? sw1 : 0.0f)
                + ((wv > 2) ? sw2 : 0.0f);
    float excl = __shfl_up(v, 1);
    if (lane == 0) excl = 0.0f;
    float cum    = basev + excl;
    float trans  = __expf(cum);
    float weight = trans * (1.0f - __expf(av));
    bool  mask2  = maskA && (trans > 1e-4f);

    // ---------------- Phase E: final 64->3 via transposed MFMA ---------------
    float wm = mask2 ? weight : 0.0f;
    // weights for rows tn*16+c via wave shuffle (all lanes execute: sources active)
    float wgt[4];
    #pragma unroll
    for (int tn = 0; tn < 4; ++tn) wgt[tn] = __shfl(wm, tn * 16 + c, 64);

    const unsigned short* __restrict__ w2eP = (const unsigned short*)(ws + WS_W2E);
    short8 w2f[2];
    w2f[0] = *(const short8*)(w2eP + (0 * 64 + lane) * 8);
    w2f[1] = *(const short8*)(w2eP + (1 * 64 + lane) * 8);

    floatx4 eacc[4];
    #pragma unroll
    for (int tn = 0; tn < 4; ++tn) {
        floatx4 z; z[0] = 0.0f; z[1] = 0.0f; z[2] = 0.0f; z[3] = 0.0f;
        eacc[tn] = z;
    }
    __builtin_amdgcn_s_setprio(1);
    #pragma unroll
    for (int kf = 0; kf < 2; ++kf)
        #pragma unroll
        for (int tn = 0; tn < 4; ++tn) {
            int m = mbase + tn * 16 + c;
            int gl = kf * 4 + q;
            short8 hb = *(const short8*)&fh[m * 64 + ((gl ^ (m & 7)) << 3)];
            eacc[tn] = __builtin_amdgcn_mfma_f32_16x16x32_bf16(w2f[kf], hb, eacc[tn], 0, 0, 0);
        }
    __builtin_amdgcn_s_setprio(0);

    float r = 0.0f, g = 0.0f, b = 0.0f;
    if (q == 0) {
        float rb0 = r_b2[0], rb1 = r_b2[1], rb2v = r_b2[2];
        #pragma unroll
        for (int tn = 0; tn < 4; ++tn) {
            float wgtv = wgt[tn];
            r += wgtv / (1.0f + __expf(-(eacc[tn][0] + rb0)));
            g += wgtv / (1.0f + __expf(-(eacc[tn][1] + rb1)));
            b += wgtv / (1.0f + __expf(-(eacc[tn][2] + rb2v)));
        }
    }
    #pragma unroll
    for (int off = 8; off > 0; off >>= 1) {
        r += __shfl_xor(r, off);
        g += __shfl_xor(g, off);
        b += __shfl_xor(b, off);
    }
    // cross-wave partials via w1s (LDS), final sum by tid 0
    if (lane == 0) {
        w1s[644 + wv * 3 + 0] = r;
        w1s[644 + wv * 3 + 1] = g;
        w1s[644 + wv * 3 + 2] = b;
    }
    __syncthreads();
    if (tid == 0) {
        out[ray * 3 + 0] = w1s[644] + w1s[647] + w1s[650] + w1s[653];
        out[ray * 3 + 1] = w1s[645] + w1s[648] + w1s[651] + w1s[654];
        out[ray * 3 + 2] = w1s[646] + w1s[649] + w1s[652] + w1s[655];
    }
}

extern "C" void kernel_launch(void* const* d_in, const int* in_sizes, int n_in,
                              void* d_out, int out_size, void* d_ws, size_t ws_size,
                              hipStream_t stream) {
    const int n_rays = in_sizes[0] / 3;   // 4096
    nerf_prep<<<32, 256, 0, stream>>>(
        (const float*)d_in[3], (const float*)d_in[4], (const float*)d_in[5],
        (const float*)d_in[6], (const float*)d_in[7], (const float*)d_in[8],
        (const float*)d_in[9], (const float*)d_in[11], (unsigned char*)d_ws);
    nerf_mfma<<<n_rays, 256, 0, stream>>>(
        (const float*)d_in[0],  (const float*)d_in[1],  (const float*)d_in[2],
        (const float*)d_in[6],  (const float*)d_in[9],  (const float*)d_in[10],
        (const float*)d_in[12],
        (const unsigned char*)d_ws, (float*)d_out);
}

// Round 13
// 155.623 us; speedup vs baseline: 1.0890x; 1.0163x over previous
//
#include <hip/hip_runtime.h>
#include <hip/hip_bf16.h>
#include <math.h>
#include <stdint.h>

#define S    256
#define GN   128

typedef __attribute__((ext_vector_type(8))) short  short8;   // 8 bf16
typedef __attribute__((ext_vector_type(4))) float  floatx4;  // MFMA C/D
typedef __attribute__((ext_vector_type(2))) float  float2v;  // v_pk_*_f32 pair

// workspace layout (bytes)
#define WS_BHI 0          // ushort[4*4*64*8] = 16384 B  (f_w2 bf16, frag order)
#define WS_RW1 16384      // ushort[2*4*64*8] =  8192 B  (r_w1 bf16, frag order)
#define WS_B2S 24576      // float  (b2.s_w + s_b)
#define WS_WS2 24592      // float[128]  (W2 @ s_w, fp32)
#define WS_W1P 25104      // float[64*8] pair-interleaved layer-1 = 2048 B
#define WS_W2E 27152      // ushort[2*64*8] = 2048 B (r_w2^T bf16, A-frag order)

__device__ __forceinline__ unsigned short bf16_rtne(float f) {
    uint32_t u = __builtin_bit_cast(uint32_t, f);
    uint32_t r = (u + 0x7fffu + ((u >> 16) & 1u)) >> 16;
    return (unsigned short)r;
}
__device__ __forceinline__ uint32_t cvt_pk_bf16(float a, float b) {
    float2 hh; hh.x = a; hh.y = b;
    __hip_bfloat162 pk = __float22bfloat162_rn(hh);   // v_cvt_pk_bf16_f32
    uint32_t u; __builtin_memcpy(&u, &pk, 4);
    return u;
}

// ---------- pre-pack kernel: weights -> bf16 in MFMA fragment order ----------
// R30: fully flattened. bhi/rw/w2e = one 13312-element range, 1 elem/thread
// (blocks 0..51, no loops). Block 52: ws2 with 2 threads/output, float4
// loads, 4-way split accumulators + 1 shfl_xor (serial dep chain 64 -> 8).
// Block 53: b2s (vectorized, split accs) + w1pk. All writes disjoint.
__global__ __launch_bounds__(256)
void nerf_prep(const float* __restrict__ f_w1, const float* __restrict__ f_b1,
               const float* __restrict__ f_w2, const float* __restrict__ f_b2,
               const float* __restrict__ s_w,  const float* __restrict__ s_b,
               const float* __restrict__ r_w1, const float* __restrict__ r_w2,
               unsigned char* __restrict__ ws)
{
    const int tid = threadIdx.x;
    const int bid = blockIdx.x;
    const int gid = bid * 256 + tid;

    if (gid < 8192) {                          // bhi: 1 elem/thread
        int i = gid;
        int j = i & 7, L = (i >> 3) & 63, g = i >> 9;   // g = kc*4 + tn
        int tn = g & 3, kc = g >> 2;
        int q = L >> 4, cc = L & 15;
        int k = kc * 32 + q * 8 + j;
        ((unsigned short*)(ws + WS_BHI))[i] = bf16_rtne(f_w2[k * 64 + tn * 16 + cc]);
    } else if (gid < 12288) {                  // rw: 1 elem/thread
        int i = gid - 8192;
        int j = i & 7, L = (i >> 3) & 63, g = i >> 9;   // g = ks*4 + tn
        int tn = g & 3, ks = g >> 2;
        int q = L >> 4, cc = L & 15;
        int k = ks * 32 + q * 8 + j;
        ((unsigned short*)(ws + WS_RW1))[i] = bf16_rtne(r_w1[k * 64 + tn * 16 + cc]);
    } else if (gid < 13312) {                  // w2e: 1 elem/thread
        int i = gid - 12288;
        int j = i & 7, L = (i >> 3) & 63, kf = i >> 9;
        int q = L >> 4, ch = L & 15;
        int k = kf * 32 + q * 8 + j;
        ((unsigned short*)(ws + WS_W2E))[i] =
            (ch < 3) ? bf16_rtne(r_w2[k * 3 + ch]) : (unsigned short)0;
    }

    if (bid == 52) {                           // ws2 = W2 @ s_w: 2 thr/output
        int o = tid >> 1, h = tid & 1;         // pair is wave-local (adjacent)
        const float4* row = (const float4*)(f_w2 + o * 64 + h * 32);
        const float4* sv  = (const float4*)(s_w + h * 32);
        float a0 = 0.0f, a1 = 0.0f, a2 = 0.0f, a3 = 0.0f;
        #pragma unroll
        for (int j2 = 0; j2 < 8; ++j2) {
            float4 w = row[j2];
            float4 s = sv[j2];
            a0 += w.x * s.x; a1 += w.y * s.y; a2 += w.z * s.z; a3 += w.w * s.w;
        }
        float acc = (a0 + a1) + (a2 + a3);
        acc += __shfl_xor(acc, 1);
        if (h == 0) ((float*)(ws + WS_WS2))[o] = acc;
    }

    if (bid == 53) {
        if (tid == 0) {                        // b2s = b2 . s_w + s_b
            const float4* bv = (const float4*)f_b2;
            const float4* sv = (const float4*)s_w;
            float a0 = 0.0f, a1 = 0.0f, a2 = 0.0f, a3 = 0.0f;
            #pragma unroll
            for (int j2 = 0; j2 < 16; ++j2) {
                float4 b = bv[j2];
                float4 s = sv[j2];
                a0 += b.x * s.x; a1 += b.y * s.y; a2 += b.z * s.z; a3 += b.w * s.w;
            }
            *(float*)(ws + WS_B2S) = s_b[0] + (a0 + a1) + (a2 + a3);
        }
        // layer-1 pair-interleaved pack (64 threads, 1 pair each):
        //   {wx0,wx1, wy0,wy1, wz0,wz1, b0,b1}
        if (tid >= 128 && tid < 192) {
            int pp = tid - 128;
            float* w1pk = (float*)(ws + WS_W1P);
            int k0 = 2 * pp, k1 = 2 * pp + 1;
            w1pk[pp * 8 + 0] = f_w1[k0];       w1pk[pp * 8 + 1] = f_w1[k1];
            w1pk[pp * 8 + 2] = f_w1[128 + k0]; w1pk[pp * 8 + 3] = f_w1[128 + k1];
            w1pk[pp * 8 + 4] = f_w1[256 + k0]; w1pk[pp * 8 + 5] = f_w1[256 + k1];
            w1pk[pp * 8 + 6] = f_b1[k0];       w1pk[pp * 8 + 7] = f_b1[k1];
        }
    }
}

// ---------------------------- main kernel -----------------------------------
// R30 main kernel = R28 VERBATIM (79.4 us best; R29 measured 80.9 on identical
// code -> +-1.5 us machine variance band). Tripwires: VGPR 64, LDS 35840,
// WRITE ~1.3 MB, conflicts 0.
// R28 history: removed phase-D wave_barrier (MFMA||VALU epilogue overlap) +
// widened phase-D setprio window -> 83.8 -> 79.4. R27: setprio on MFMA
// clusters (+2.6%). R26: scan via LDS slots (+2.3%). R25: dedicated w1s, no
// mid-phase-B barrier.
__global__ __launch_bounds__(256, 4)
void nerf_mfma(const float* __restrict__ rays_o,
               const float* __restrict__ rays_d,
               const float* __restrict__ grid,
               const float* __restrict__ f_b2,
               const float* __restrict__ r_w1,
               const float* __restrict__ r_b1,
               const float* __restrict__ r_b2,
               const unsigned char* __restrict__ ws,
               float* __restrict__ out)
{
    // fh: bf16 [256 rows][64], XOR-swizzled in 8-ushort groups: conflict-free
    // b128. Wave-private throughout.
    __shared__ __align__(16) unsigned short fh[256 * 64];
    // w1s: [0..511] layer-1 pack, [512..639] ws2, [640..643] sWaveSum,
    //      [644..655] sPart.
    __shared__ __align__(16) float w1s[656];

    const int tid   = threadIdx.x;
    const int ray   = blockIdx.x;
    const int lane  = tid & 63;
    const int wv    = tid >> 6;
    const int q     = lane >> 4;
    const int c     = lane & 15;
    const int mbase = wv * 64;
    const int d01   = 72 - ((c >> 3) << 4);   // i1 - i0 in the epilogue swizzle

    // stage layer-1 pack (2 KB) + ws2 (512 B) into dedicated LDS
    if (tid < 128) {
        ((float4*)w1s)[tid] = ((const float4*)(ws + WS_W1P))[tid];
        w1s[512 + tid]      = ((const float*)(ws + WS_WS2))[tid];
    }

    // ---------------- Phase A: geometry + grid sample (thread = sample) ------
    const float stop = 1.0f - 1.0f / (float)(S + 2);
    const float step = stop / (float)S;
    float u0 = (float)tid * step;
    float u1 = (float)(tid + 1) * step;
    float t    = (u0 < 0.5f) ? 2.0f * u0 : 1.0f / (2.0f - 2.0f * u0);
    float tn_  = (u1 < 0.5f) ? 2.0f * u1 : 1.0f / (2.0f - 2.0f * u1);
    float dist = tn_ - t;

    float ox = rays_o[ray * 3 + 0], oy = rays_o[ray * 3 + 1], oz = rays_o[ray * 3 + 2];
    float dxv = rays_d[ray * 3 + 0], dyv = rays_d[ray * 3 + 1], dzv = rays_d[ray * 3 + 2];

    float px = ox + dxv * t, py = oy + dyv * t, pz = oz + dzv * t;
    float nrm = sqrtf(px * px + py * py + pz * pz);
    float scale = (nrm <= 1.0f) ? 0.5f : (2.0f - 1.0f / nrm) / nrm * 0.5f;
    float cx = px * scale, cy = py * scale, cz = pz * scale;

    float ix = ((cx + 1.0f) * (float)GN - 1.0f) * 0.5f;
    float iy = ((cy + 1.0f) * (float)GN - 1.0f) * 0.5f;
    float iz = ((cz + 1.0f) * (float)GN - 1.0f) * 0.5f;
    float fx0 = floorf(ix), fy0 = floorf(iy), fz0 = floorf(iz);
    float fx = ix - fx0, fy = iy - fy0, fz = iz - fz0;
    int x0 = (int)fx0, y0 = (int)fy0, z0 = (int)fz0;
    int x1 = x0 + 1, y1 = y0 + 1, z1 = z0 + 1;

    // contracted coords strictly inside [-1,1] -> x0 in [-1,127], x1 in [0,128].
    // Only boundary taps can be invalid: zero the per-axis weight, clamp the
    // index. 0*g == 0 exactly; product order (wx*wy)*wz matches branchy version.
    float wxv[2], wyv[2], wzv[2];
    wxv[0] = (x0 >= 0) ? (1.0f - fx) : 0.0f;  wxv[1] = (x1 < GN) ? fx : 0.0f;
    wyv[0] = (y0 >= 0) ? (1.0f - fy) : 0.0f;  wyv[1] = (y1 < GN) ? fy : 0.0f;
    wzv[0] = (z0 >= 0) ? (1.0f - fz) : 0.0f;  wzv[1] = (z1 < GN) ? fz : 0.0f;
    int xc[2], yb[2], zb[2];
    xc[0] = (x0 < 0) ? 0 : x0;              xc[1] = (x1 > GN - 1) ? GN - 1 : x1;
    yb[0] = ((y0 < 0) ? 0 : y0) * GN;       yb[1] = ((y1 > GN - 1) ? GN - 1 : y1) * GN;
    zb[0] = ((z0 < 0) ? 0 : z0) * (GN*GN);  zb[1] = ((z1 > GN - 1) ? GN - 1 : z1) * (GN*GN);

    float occ = 0.0f;
    #pragma unroll
    for (int dzc = 0; dzc < 2; ++dzc)
    #pragma unroll
    for (int dyc = 0; dyc < 2; ++dyc)
    #pragma unroll
    for (int dxc = 0; dxc < 2; ++dxc) {
        float w = (wxv[dxc] * wyv[dyc]) * wzv[dzc];
        occ += w * grid[zb[dzc] + yb[dyc] + xc[dxc]];
    }
    bool maskA = occ > 0.01f;

    __syncthreads();   // w1s staged

    // ------- Phase B+C: feat GEMM in two tm-passes (acc[2][4] = 32 AGPR) -----
    const unsigned short* __restrict__ bhiP = (const unsigned short*)(ws + WS_BHI);
    float sgv[4] = {0.0f, 0.0f, 0.0f, 0.0f};   // all reads/writes literal-indexed

    #pragma unroll 1
    for (int ph = 0; ph < 2; ++ph) {
        // coords of the A-fragment rows for THIS pass (literal-indexed pair;
        // ph only appears in the shuffle source lane -> no scratch)
        float cxs[2], cys[2], czs[2];
        #pragma unroll
        for (int tm = 0; tm < 2; ++tm) {
            int src = (ph * 2 + tm) * 16 + c;
            cxs[tm] = __shfl(cx, src, 64);
            cys[tm] = __shfl(cy, src, 64);
            czs[tm] = __shfl(cz, src, 64);
        }

        floatx4 acc[2][4];
        {
            float b2v[4];
            #pragma unroll
            for (int tn = 0; tn < 4; ++tn) b2v[tn] = f_b2[tn * 16 + c];
            #pragma unroll
            for (int tm = 0; tm < 2; ++tm)
                #pragma unroll
                for (int tn = 0; tn < 4; ++tn) {
                    floatx4 v; v[0] = b2v[tn]; v[1] = b2v[tn]; v[2] = b2v[tn]; v[3] = b2v[tn];
                    acc[tm][tn] = v;
                }
        }
        float2v sig2[2];
        sig2[0][0] = 0.0f; sig2[0][1] = 0.0f;
        sig2[1][0] = 0.0f; sig2[1][1] = 0.0f;

        #pragma unroll 2
        for (int kc = 0; kc < 4; ++kc) {
            const int k0  = kc * 32 + q * 8;
            const int pp0 = kc * 16 + q * 4;
            const float4* w1q4 = (const float4*)&w1s[pp0 * 8];
            float ws2r[8];
            *(float4*)(ws2r)     = *(const float4*)&w1s[512 + k0];
            *(float4*)(ws2r + 4) = *(const float4*)&w1s[512 + k0 + 4];

            uint32_t packed[2][4];
            #pragma unroll
            for (int p = 0; p < 4; ++p) {
                float4 q0 = w1q4[2 * p];         // {wx0,wx1, wy0,wy1}
                float4 q1 = w1q4[2 * p + 1];     // {wz0,wz1, b0, b1}
                float2v wx2 = {q0.x, q0.y};
                float2v wy2 = {q0.z, q0.w};
                float2v wz2 = {q1.x, q1.y};
                float2v bb2 = {q1.z, q1.w};
                float2v wsp = {ws2r[2 * p], ws2r[2 * p + 1]};
                #pragma unroll
                for (int tm = 0; tm < 2; ++tm) {
                    float2v h2 = bb2;
                    h2 = __builtin_elementwise_fma((float2v){cxs[tm], cxs[tm]}, wx2, h2);
                    h2 = __builtin_elementwise_fma((float2v){cys[tm], cys[tm]}, wy2, h2);
                    h2 = __builtin_elementwise_fma((float2v){czs[tm], czs[tm]}, wz2, h2);
                    h2 = __builtin_elementwise_max(h2, (float2v){0.0f, 0.0f});
                    sig2[tm] = __builtin_elementwise_fma(h2, wsp, sig2[tm]);
                    packed[tm][p] = cvt_pk_bf16(h2[0], h2[1]);
                }
            }
            short8 Ah[2];
            #pragma unroll
            for (int tm = 0; tm < 2; ++tm) {
                uint4 v4 = {packed[tm][0], packed[tm][1], packed[tm][2], packed[tm][3]};
                Ah[tm] = __builtin_bit_cast(short8, v4);
            }
            const int bbase = (kc * 4) * 512 + lane * 8;
            __builtin_amdgcn_s_setprio(1);
            #pragma unroll
            for (int tn = 0; tn < 4; ++tn) {
                short8 bh = *(const short8*)(bhiP + bbase + tn * 512);
                #pragma unroll
                for (int tm = 0; tm < 2; ++tm)
                    acc[tm][tn] = __builtin_amdgcn_mfma_f32_16x16x32_bf16(Ah[tm], bh, acc[tm][tn], 0, 0, 0);
            }
            __builtin_amdgcn_s_setprio(0);
        }

        // NO barrier: fh is wave-private (staging lives in w1s).

        // phase C for this pass: feat rows -> fh, sigma partials collapse
        #pragma unroll
        for (int tm = 0; tm < 2; ++tm)
            #pragma unroll
            for (int tn = 0; tn < 4; ++tn)
                #pragma unroll
                for (int pr = 0; pr < 2; ++pr) {
                    uint32_t u = cvt_pk_bf16(acc[tm][tn][2 * pr], acc[tm][tn][2 * pr + 1]);
                    int m0 = mbase + (ph * 2 + tm) * 16 + q * 4 + 2 * pr;
                    int i0 = m0 * 64 + c + (((tn * 2) ^ (m0 & 7)) << 3);
                    fh[i0]       = (unsigned short)u;
                    fh[i0 + d01] = (unsigned short)(u >> 16);
                }
        {
            float s0 = sig2[0][0] + sig2[0][1];
            s0 += __shfl_xor(s0, 16);
            s0 += __shfl_xor(s0, 32);
            float s1 = sig2[1][0] + sig2[1][1];
            s1 += __shfl_xor(s1, 16);
            s1 += __shfl_xor(s1, 32);
            if (ph == 0) { sgv[0] = s0; sgv[1] = s1; }   // wave-uniform branch,
            else         { sgv[2] = s0; sgv[3] = s1; }   // literal indices
        }
    }

    // ------- per-lane sigma: sgv[] is q-broadcast; own row = lane -> sgv[q] --
    float av;
    {
        float b2s = *(const float*)(ws + WS_B2S);
        float s01  = (q & 1) ? sgv[1] : sgv[0];
        float s23  = (q & 1) ? sgv[3] : sgv[2];
        float sa = ((q & 2) ? s23 : s01) + b2s;
        float sg = maskA ? (fmaxf(sa, 0.0f) + __logf(1.0f + __expf(-fabsf(sa)))) : 0.0f;
        av = -sg * dist;
    }

    // hd[] uniform loads: latency hides under the scan below
    float hd[4];
    #pragma unroll
    for (int tn = 0; tn < 4; ++tn) {
        int n = tn * 16 + c;
        hd[tn] = r_b1[n] + dxv * r_w1[64 * 64 + n] + dyv * r_w1[65 * 64 + n] + dzv * r_w1[66 * 64 + n];
    }

    // ---------------- transmittance scan, part 1 (intra-wave) ----------------
    float v = av;
    #pragma unroll
    for (int off = 1; off < 64; off <<= 1) {
        float u2 = __shfl_up(v, off);
        if (lane >= off) v += u2;
    }
    // LDS slot-write NOW; barrier + dependent read happen AFTER phase D, so
    // even the short LDS latency hides under the rgb-hidden GEMM.
    if (lane == 63 && wv < 3) w1s[640 + wv] = v;

    // ---------------- Phase D: rgb-hidden GEMM, two tm-passes ----------------
    const unsigned short* __restrict__ rwP = (const unsigned short*)(ws + WS_RW1);

    #pragma unroll 1
    for (int ph = 0; ph < 2; ++ph) {
        // setprio window opens BEFORE the operand loads (matches phase B/E
        // window shape): afr ds_reads + rb loads are the MFMA critical path.
        __builtin_amdgcn_s_setprio(1);

        // pass-0 epilogue writes rows mbase+0..31; pass-1 afr reads rows
        // mbase+32..63 -- disjoint, wave-private: no barrier needed.
        short8 afr[2][2];
        #pragma unroll
        for (int tm = 0; tm < 2; ++tm)
            #pragma unroll
            for (int ks = 0; ks < 2; ++ks) {
                int m = mbase + (ph * 2 + tm) * 16 + c;
                int gl = ks * 4 + q;
                afr[tm][ks] = *(const short8*)&fh[m * 64 + ((gl ^ (m & 7)) << 3)];
            }

        floatx4 acc[2][4];
        #pragma unroll
        for (int tm = 0; tm < 2; ++tm)
            #pragma unroll
            for (int tn = 0; tn < 4; ++tn) {
                floatx4 z; z[0] = 0.0f; z[1] = 0.0f; z[2] = 0.0f; z[3] = 0.0f;
                acc[tm][tn] = z;
            }
        #pragma unroll
        for (int ks = 0; ks < 2; ++ks)
            #pragma unroll
            for (int tn = 0; tn < 4; ++tn) {
                short8 rb = *(const short8*)(rwP + ((ks * 4 + tn) * 64 + lane) * 8);
                #pragma unroll
                for (int tm = 0; tm < 2; ++tm)
                    acc[tm][tn] = __builtin_amdgcn_mfma_f32_16x16x32_bf16(afr[tm][ks], rb, acc[tm][tn], 0, 0, 0);
            }
        __builtin_amdgcn_s_setprio(0);

        // NO wave_barrier: each acc's epilogue depends only on its own MFMA
        // chain -- let the compiler overlap early accs' cvt_pk/ds_write with
        // late MFMAs (intra-wave MFMA||VALU pipe overlap).
        #pragma unroll
        for (int tm = 0; tm < 2; ++tm)
            #pragma unroll
            for (int tn = 0; tn < 4; ++tn)
                #pragma unroll
                for (int pr = 0; pr < 2; ++pr) {
                    float2v a2 = {acc[tm][tn][2 * pr], acc[tm][tn][2 * pr + 1]};
                    a2 = a2 + (float2v){hd[tn], hd[tn]};
                    a2 = __builtin_elementwise_max(a2, (float2v){0.0f, 0.0f});
                    uint32_t u = cvt_pk_bf16(a2[0], a2[1]);
                    int m0 = mbase + (ph * 2 + tm) * 16 + q * 4 + 2 * pr;
                    int i0 = m0 * 64 + c + (((tn * 2) ^ (m0 & 7)) << 3);
                    fh[i0]       = (unsigned short)u;
                    fh[i0 + d01] = (unsigned short)(u >> 16);
                }
    }

    // ---------------- scan part 2: cross-wave prefix (LDS slot read) ---------
    __syncthreads();   // orders the w1s slot writes
    float sw0 = w1s[640];
    float sw1 = w1s[641];
    float sw2 = w1s[642];
    float basev = ((wv > 0) ? sw0 : 0.0f) + ((wv > 1) ? sw1 : 0.0f)
                + ((wv > 2) ? sw2 : 0.0f);
    float excl = __shfl_up(v, 1);
    if (lane == 0) excl = 0.0f;
    float cum    = basev + excl;
    float trans  = __expf(cum);
    float weight = trans * (1.0f - __expf(av));
    bool  mask2  = maskA && (trans > 1e-4f);

    // ---------------- Phase E: final 64->3 via transposed MFMA ---------------
    float wm = mask2 ? weight : 0.0f;
    // weights for rows tn*16+c via wave shuffle (all lanes execute: sources active)
    float wgt[4];
    #pragma unroll
    for (int tn = 0; tn < 4; ++tn) wgt[tn] = __shfl(wm, tn * 16 + c, 64);

    const unsigned short* __restrict__ w2eP = (const unsigned short*)(ws + WS_W2E);
    short8 w2f[2];
    w2f[0] = *(const short8*)(w2eP + (0 * 64 + lane) * 8);
    w2f[1] = *(const short8*)(w2eP + (1 * 64 + lane) * 8);

    floatx4 eacc[4];
    #pragma unroll
    for (int tn = 0; tn < 4; ++tn) {
        floatx4 z; z[0] = 0.0f; z[1] = 0.0f; z[2] = 0.0f; z[3] = 0.0f;
        eacc[tn] = z;
    }
    __builtin_amdgcn_s_setprio(1);
    #pragma unroll
    for (int kf = 0; kf < 2; ++kf)
        #pragma unroll
        for (int tn = 0; tn < 4; ++tn) {
            int m = mbase + tn * 16 + c;
            int gl = kf * 4 + q;
            short8 hb = *(const short8*)&fh[m * 64 + ((gl ^ (m & 7)) << 3)];
            eacc[tn] = __builtin_amdgcn_mfma_f32_16x16x32_bf16(w2f[kf], hb, eacc[tn], 0, 0, 0);
        }
    __builtin_amdgcn_s_setprio(0);

    float r = 0.0f, g = 0.0f, b = 0.0f;
    if (q == 0) {
        float rb0 = r_b2[0], rb1 = r_b2[1], rb2v = r_b2[2];
        #pragma unroll
        for (int tn = 0; tn < 4; ++tn) {
            float wgtv = wgt[tn];
            r += wgtv / (1.0f + __expf(-(eacc[tn][0] + rb0)));
            g += wgtv / (1.0f + __expf(-(eacc[tn][1] + rb1)));
            b += wgtv / (1.0f + __expf(-(eacc[tn][2] + rb2v)));
        }
    }
    #pragma unroll
    for (int off = 8; off > 0; off >>= 1) {
        r += __shfl_xor(r, off);
        g += __shfl_xor(g, off);
        b += __shfl_xor(b, off);
    }
    // cross-wave partials via w1s (LDS), final sum by tid 0
    if (lane == 0) {
        w1s[644 + wv * 3 + 0] = r;
        w1s[644 + wv * 3 + 1] = g;
        w1s[644 + wv * 3 + 2] = b;
    }
    __syncthreads();
    if (tid == 0) {
        out[ray * 3 + 0] = w1s[644] + w1s[647] + w1s[650] + w1s[653];
        out[ray * 3 + 1] = w1s[645] + w1s[648] + w1s[651] + w1s[654];
        out[ray * 3 + 2] = w1s[646] + w1s[649] + w1s[652] + w1s[655];
    }
}

extern "C" void kernel_launch(void* const* d_in, const int* in_sizes, int n_in,
                              void* d_out, int out_size, void* d_ws, size_t ws_size,
                              hipStream_t stream) {
    const int n_rays = in_sizes[0] / 3;   // 4096
    nerf_prep<<<54, 256, 0, stream>>>(
        (const float*)d_in[3], (const float*)d_in[4], (const float*)d_in[5],
        (const float*)d_in[6], (const float*)d_in[7], (const float*)d_in[8],
        (const float*)d_in[9], (const float*)d_in[11], (unsigned char*)d_ws);
    nerf_mfma<<<n_rays, 256, 0, stream>>>(
        (const float*)d_in[0],  (const float*)d_in[1],  (const float*)d_in[2],
        (const float*)d_in[6],  (const float*)d_in[9],  (const float*)d_in[10],
        (const float*)d_in[12],
        (const unsigned char*)d_ws, (float*)d_out);
}